// Round 2
// baseline (2456.557 us; speedup 1.0000x reference)
//
#include <hip/hip_runtime.h>

typedef unsigned short u16;
typedef unsigned short u16x8 __attribute__((ext_vector_type(8)));
typedef __bf16 bf16x8 __attribute__((ext_vector_type(8)));
typedef float f32x4 __attribute__((ext_vector_type(4)));

// B=2, T=2048, N_EMBD=2048, D_INNER=4096, N_HEADS=32, HEAD_DIM=128, D_STATE=128,
// PROJ=8480, CHUNK=64, n_chunks=32. All external tensors are FP32.
// proj row: [0,4096) gate | [4096,8192) ssm_in | [8192,8224) dt | [8224,8352) B | [8352,8480) C

__device__ __forceinline__ float bf2f(u16 u) {
    union { unsigned int i; float f; } v; v.i = ((unsigned int)u) << 16; return v.f;
}
__device__ __forceinline__ u16 f2bf(float f) {
    unsigned int u = __float_as_uint(f);
    u += 0x7fffu + ((u >> 16) & 1u);   // RNE
    return (u16)(u >> 16);
}

// ---------------- K1: RMSNorm (fp32 in, bf16 out) ----------------
__global__ __launch_bounds__(256) void k_rmsnorm(const float* __restrict__ x,
                                                 const float* __restrict__ scale,
                                                 u16* __restrict__ h) {
    int row = blockIdx.x, tid = threadIdx.x;
    const float4* xr = reinterpret_cast<const float4*>(x + (size_t)row * 2048);
    float4 v0 = xr[tid], v1 = xr[tid + 256];
    float ss = v0.x*v0.x + v0.y*v0.y + v0.z*v0.z + v0.w*v0.w
             + v1.x*v1.x + v1.y*v1.y + v1.z*v1.z + v1.w*v1.w;
#pragma unroll
    for (int off = 32; off > 0; off >>= 1) ss += __shfl_down(ss, off, 64);
    __shared__ float red[4];
    if ((tid & 63) == 0) red[tid >> 6] = ss;
    __syncthreads();
    float r = rsqrtf((red[0] + red[1] + red[2] + red[3]) * (1.f / 2048.f) + 1e-6f);
    const float4* sc = reinterpret_cast<const float4*>(scale);
    float4 s0 = sc[tid], s1 = sc[tid + 256];
    ushort4 o0, o1;
    o0.x = f2bf(v0.x * r * s0.x); o0.y = f2bf(v0.y * r * s0.y);
    o0.z = f2bf(v0.z * r * s0.z); o0.w = f2bf(v0.w * r * s0.w);
    o1.x = f2bf(v1.x * r * s1.x); o1.y = f2bf(v1.y * r * s1.y);
    o1.z = f2bf(v1.z * r * s1.z); o1.w = f2bf(v1.w * r * s1.w);
    ushort4* hr = reinterpret_cast<ushort4*>(h + (size_t)row * 2048);
    hr[tid] = o0; hr[tid + 256] = o1;
}

// ---------------- K2/K8: MFMA GEMM. A: bf16 MxK. B: FP32 KxN (converted on stage).
// BF16_OUT: write bf16 Cb. else: write fp32 Cf (+ fp32 resid). M%64==0, K%32==0, N guarded.
template <bool BF16_OUT>
__global__ __launch_bounds__(256) void k_gemm(const u16* __restrict__ A,
                                              const float* __restrict__ B,
                                              u16* __restrict__ Cb,
                                              float* __restrict__ Cf,
                                              const float* __restrict__ resid,
                                              int M, int N, int K) {
    __shared__ u16 As[64][40];   // [m][k] ; row stride 80B (16B-aligned)
    __shared__ u16 Bs[64][40];   // [n][k]
    int m0 = blockIdx.y * 64, n0 = blockIdx.x * 64;
    int tid = threadIdx.x, lane = tid & 63, w = tid >> 6;
    int wm = (w >> 1) * 32, wn = (w & 1) * 32;
    int r = lane & 15, q = lane >> 4;
    f32x4 acc[2][2];
#pragma unroll
    for (int a = 0; a < 2; ++a)
#pragma unroll
        for (int b = 0; b < 2; ++b) acc[a][b] = (f32x4){0.f, 0.f, 0.f, 0.f};

    int arow = tid >> 2, acol = (tid & 3) * 8;      // 64 rows x 32 k
    int bkrow = tid >> 3, bncol = (tid & 7) * 8;    // 32 k-rows x 64 n

    for (int k0 = 0; k0 < K; k0 += 32) {
        uint4 av = *reinterpret_cast<const uint4*>(A + (size_t)(m0 + arow) * K + k0 + acol);
        *reinterpret_cast<uint4*>(&As[arow][acol]) = av;
        int gn = n0 + bncol;
        u16 tmp[8];
        if (gn + 8 <= N) {
            const float4* bp = reinterpret_cast<const float4*>(B + (size_t)(k0 + bkrow) * N + gn);
            float4 b0 = bp[0], b1 = bp[1];
            tmp[0] = f2bf(b0.x); tmp[1] = f2bf(b0.y); tmp[2] = f2bf(b0.z); tmp[3] = f2bf(b0.w);
            tmp[4] = f2bf(b1.x); tmp[5] = f2bf(b1.y); tmp[6] = f2bf(b1.z); tmp[7] = f2bf(b1.w);
        } else {
#pragma unroll
            for (int i = 0; i < 8; ++i)
                tmp[i] = (gn + i < N) ? f2bf(B[(size_t)(k0 + bkrow) * N + gn + i]) : (u16)0;
        }
#pragma unroll
        for (int i = 0; i < 8; ++i) Bs[bncol + i][bkrow] = tmp[i];
        __syncthreads();

        bf16x8 a0 = __builtin_bit_cast(bf16x8, *reinterpret_cast<const u16x8*>(&As[wm + r][q * 8]));
        bf16x8 a1 = __builtin_bit_cast(bf16x8, *reinterpret_cast<const u16x8*>(&As[wm + 16 + r][q * 8]));
        bf16x8 b0 = __builtin_bit_cast(bf16x8, *reinterpret_cast<const u16x8*>(&Bs[wn + r][q * 8]));
        bf16x8 b1 = __builtin_bit_cast(bf16x8, *reinterpret_cast<const u16x8*>(&Bs[wn + 16 + r][q * 8]));
        acc[0][0] = __builtin_amdgcn_mfma_f32_16x16x32_bf16(a0, b0, acc[0][0], 0, 0, 0);
        acc[0][1] = __builtin_amdgcn_mfma_f32_16x16x32_bf16(a0, b1, acc[0][1], 0, 0, 0);
        acc[1][0] = __builtin_amdgcn_mfma_f32_16x16x32_bf16(a1, b0, acc[1][0], 0, 0, 0);
        acc[1][1] = __builtin_amdgcn_mfma_f32_16x16x32_bf16(a1, b1, acc[1][1], 0, 0, 0);
        __syncthreads();
    }
    // C/D: col = lane&15, row = (lane>>4)*4 + reg  [m89/m91 verified]
#pragma unroll
    for (int mt = 0; mt < 2; ++mt)
#pragma unroll
        for (int nt = 0; nt < 2; ++nt)
#pragma unroll
            for (int rg = 0; rg < 4; ++rg) {
                int gm = m0 + wm + mt * 16 + q * 4 + rg;
                int gn = n0 + wn + nt * 16 + r;
                if (gn < N) {
                    float vv = acc[mt][nt][rg];
                    if (BF16_OUT) {
                        Cb[(size_t)gm * N + gn] = f2bf(vv);
                    } else {
                        if (resid) vv += resid[(size_t)gm * N + gn];
                        Cf[(size_t)gm * N + gn] = vv;
                    }
                }
            }
}

// ---------------- K3: depthwise causal conv(4) + bias + SiLU ----------------
__global__ __launch_bounds__(256) void k_conv(const u16* __restrict__ proj,
                                              const float* __restrict__ cw,
                                              const float* __restrict__ cb,
                                              u16* __restrict__ xs) {
    int bt = blockIdx.x;
    int b = bt >> 11, t = bt & 2047;
    int tid = threadIdx.x;
#pragma unroll
    for (int i = 0; i < 16; ++i) {
        int ch = tid + i * 256;
        float acc = cb[ch];
#pragma unroll
        for (int k = 0; k < 4; ++k) {
            int tt = t - 3 + k;
            if (tt >= 0)
                acc += cw[k * 4096 + ch] * bf2f(proj[(size_t)(b * 2048 + tt) * 8480 + 4096 + ch]);
        }
        float s = acc / (1.f + expf(-acc));
        xs[(size_t)bt * 4096 + ch] = f2bf(s);
    }
}

// ---------------- K4: dt=softplus, per-chunk inclusive cumsum of A*dt ----------------
// dt/cumla layout: [b][h][c][j]
__global__ __launch_bounds__(64) void k_dt(const u16* __restrict__ proj,
                                           const float* __restrict__ A_log,
                                           const float* __restrict__ dt_bias,
                                           float* __restrict__ dt,
                                           float* __restrict__ cumla) {
    int bid = blockIdx.x;
    int b = bid >> 10, hh = (bid >> 5) & 31, c = bid & 31;
    int j = threadIdx.x;
    int t = c * 64 + j;
    float z = bf2f(proj[(size_t)(b * 2048 + t) * 8480 + 8192 + hh]) + dt_bias[hh];
    float dtv = (z > 20.f) ? z : log1pf(expf(z));
    float v = -expf(A_log[hh]) * dtv;
#pragma unroll
    for (int off = 1; off < 64; off <<= 1) {
        float pv = __shfl_up(v, off, 64);
        if (j >= off) v += pv;
    }
    int base = ((b * 32 + hh) * 32 + c) * 64;
    dt[base + j] = dtv;
    cumla[base + j] = v;
}

// ---------------- K5: intra-chunk y + local chunk state ----------------
__global__ __launch_bounds__(256) void k_intra(const u16* __restrict__ proj,
                                               const u16* __restrict__ xs,
                                               const float* __restrict__ dt,
                                               const float* __restrict__ cumla,
                                               u16* __restrict__ ybuf,
                                               u16* __restrict__ states) {
    __shared__ u16 Bs[64][130];
    __shared__ u16 Cs[64][130];
    __shared__ u16 Xs[64][128];
    __shared__ float Ms[64][64];
    __shared__ float dts[64], clas[64], wts[64];
    int bid = blockIdx.x;
    int b = bid >> 10, c = (bid >> 5) & 31, hh = bid & 31;
    int tid = threadIdx.x;
    int t0 = b * 2048 + c * 64;

    for (int e = tid; e < 8192; e += 256) {
        int i = e >> 7, n = e & 127;
        size_t rp = (size_t)(t0 + i) * 8480;
        Bs[i][n] = proj[rp + 8224 + n];
        Cs[i][n] = proj[rp + 8352 + n];
        Xs[i][n] = xs[(size_t)(t0 + i) * 4096 + hh * 128 + n];
    }
    if (tid < 64) {
        int base = ((b * 32 + hh) * 32 + c) * 64;
        dts[tid] = dt[base + tid];
        clas[tid] = cumla[base + tid];
    }
    __syncthreads();
    if (tid < 64) wts[tid] = expf(clas[63] - clas[tid]) * dts[tid];

    // M[i][j] = exp(cla_i - cla_j) * (C_i . B_j) * dt_j,  j<=i
    for (int e = tid; e < 4096; e += 256) {
        int i = e >> 6, j = e & 63;
        float m = 0.f;
        if (j <= i) {
            float a = 0.f;
            for (int n = 0; n < 128; ++n) a += bf2f(Cs[i][n]) * bf2f(Bs[j][n]);
            m = a * expf(clas[i] - clas[j]) * dts[j];
        }
        Ms[i][j] = m;
    }
    __syncthreads();

    for (int e = tid; e < 8192; e += 256) {
        int i = e >> 7, p = e & 127;
        float a = 0.f;
        for (int j = 0; j <= i; ++j) a += Ms[i][j] * bf2f(Xs[j][p]);
        ybuf[(size_t)(t0 + i) * 4096 + hh * 128 + p] = f2bf(a);
    }
    for (int e = tid; e < 16384; e += 256) {
        int n = e >> 7, p = e & 127;
        float a = 0.f;
        for (int j = 0; j < 64; ++j) a += wts[j] * bf2f(Bs[j][n]) * bf2f(Xs[j][p]);
        states[((size_t)((b * 32 + hh) * 32 + c)) * 16384 + n * 128 + p] = f2bf(a);
    }
}

// ---------------- K6: inter-chunk sequential scan (in-place -> start states) ----------------
__global__ __launch_bounds__(256) void k_scan(u16* __restrict__ states,
                                              const float* __restrict__ cumla) {
    int gid = blockIdx.x * 256 + threadIdx.x;
    int bh = gid >> 14;
    int np = gid & 16383;
    size_t base = (size_t)bh * 32 * 16384 + np;
    float s = 0.f;
    for (int c = 0; c < 32; ++c) {
        float cd = expf(cumla[(bh * 32 + c) * 64 + 63]);
        size_t idx = base + (size_t)c * 16384;
        float loc = bf2f(states[idx]);
        states[idx] = f2bf(s);
        s = cd * s + loc;
    }
}

// ---------------- K7: y_inter + D*x, SiLU gate (ygated may alias ybuf) ----------------
__global__ __launch_bounds__(256) void k_inter(const u16* __restrict__ proj,
                                               const u16* __restrict__ xs,
                                               const u16* __restrict__ states,
                                               const float* __restrict__ cumla,
                                               const u16* __restrict__ ybuf,
                                               const float* __restrict__ Dv,
                                               u16* __restrict__ ygated) {
    __shared__ u16 Cs[64][128];
    __shared__ u16 Ss[128][128];
    __shared__ float clas[64];
    int bid = blockIdx.x;
    int b = bid >> 10, c = (bid >> 5) & 31, hh = bid & 31;
    int tid = threadIdx.x;
    int t0 = b * 2048 + c * 64;

    for (int e = tid; e < 8192; e += 256) {
        int i = e >> 7, n = e & 127;
        Cs[i][n] = proj[(size_t)(t0 + i) * 8480 + 8352 + n];
    }
    size_t sbase = ((size_t)((b * 32 + hh) * 32 + c)) * 16384;
    for (int e = tid; e < 16384; e += 256) Ss[e >> 7][e & 127] = states[sbase + e];
    if (tid < 64) clas[tid] = cumla[((b * 32 + hh) * 32 + c) * 64 + tid];
    __syncthreads();

    for (int e = tid; e < 8192; e += 256) {
        int i = e >> 7, p = e & 127;
        float a = 0.f;
        for (int n = 0; n < 128; ++n) a += bf2f(Cs[i][n]) * bf2f(Ss[n][p]);
        float yv = expf(clas[i]) * a;
        size_t td = (size_t)(t0 + i) * 4096 + hh * 128 + p;
        float ytot = bf2f(ybuf[td]) + yv + Dv[hh * 128 + p] * bf2f(xs[td]);
        float g = bf2f(proj[(size_t)(t0 + i) * 8480 + hh * 128 + p]);
        float gact = g / (1.f + expf(-g));
        ygated[td] = f2bf(ytot * gact);
    }
}

extern "C" void kernel_launch(void* const* d_in, const int* in_sizes, int n_in,
                              void* d_out, int out_size, void* d_ws, size_t ws_size,
                              hipStream_t stream) {
    const float* x          = (const float*)d_in[0];
    const float* norm_scale = (const float*)d_in[1];
    const float* in_proj_w  = (const float*)d_in[2];
    const float* conv_w     = (const float*)d_in[3];
    const float* conv_b     = (const float*)d_in[4];
    const float* A_log      = (const float*)d_in[5];
    const float* dt_bias    = (const float*)d_in[6];
    const float* Dv         = (const float*)d_in[7];
    const float* out_w      = (const float*)d_in[8];
    float* out = (float*)d_out;

    char* ws = (char*)d_ws;
    // states [0, 67108864) ; h aliases its head [0, 16777216) (dead before states written)
    u16*   states = (u16*)(ws);
    u16*   h      = (u16*)(ws);
    u16*   proj   = (u16*)(ws + 67108864);    // 4096x8480 bf16 = 69,468,160
    u16*   xs     = (u16*)(ws + 136577024);   // 4096x4096 bf16 = 33,554,432
    u16*   ybuf   = (u16*)(ws + 170131456);   // 4096x4096 bf16 = 33,554,432 (also ygated)
    float* dt     = (float*)(ws + 203685888); // 524,288
    float* cumla  = (float*)(ws + 204210176); // 524,288
    // total 204,734,464 B

    k_rmsnorm<<<4096, 256, 0, stream>>>(x, norm_scale, h);
    k_gemm<true><<<dim3(133, 64), 256, 0, stream>>>(h, in_proj_w, proj, nullptr, nullptr, 4096, 8480, 2048);
    k_conv<<<4096, 256, 0, stream>>>(proj, conv_w, conv_b, xs);
    k_dt<<<2048, 64, 0, stream>>>(proj, A_log, dt_bias, dt, cumla);
    k_intra<<<2048, 256, 0, stream>>>(proj, xs, dt, cumla, ybuf, states);
    k_scan<<<4096, 256, 0, stream>>>(states, cumla);
    k_inter<<<2048, 256, 0, stream>>>(proj, xs, states, cumla, ybuf, Dv, ybuf);
    k_gemm<false><<<dim3(32, 64), 256, 0, stream>>>(ybuf, out_w, nullptr, out, x, 4096, 2048, 4096);
}

// Round 3
// 1326.170 us; speedup vs baseline: 1.8524x; 1.8524x over previous
//
#include <hip/hip_runtime.h>

typedef unsigned short u16;
typedef unsigned short u16x8 __attribute__((ext_vector_type(8)));
typedef __bf16 bf16x8 __attribute__((ext_vector_type(8)));
typedef float f32x4 __attribute__((ext_vector_type(4)));

// B=2, T=2048, N_EMBD=2048, D_INNER=4096, N_HEADS=32, HEAD_DIM=128, D_STATE=128,
// PROJ=8480, CHUNK=64, n_chunks=32. External tensors FP32; internal staging bf16.
// proj row: [0,4096) gate | [4096,8192) ssm_in | [8192,8224) dt | [8224,8352) B | [8352,8480) C

__device__ __forceinline__ float bf2f(u16 u) {
    union { unsigned int i; float f; } v; v.i = ((unsigned int)u) << 16; return v.f;
}
__device__ __forceinline__ u16 f2bf(float f) {
    unsigned int u = __float_as_uint(f);
    u += 0x7fffu + ((u >> 16) & 1u);   // RNE
    return (u16)(u >> 16);
}
__device__ __forceinline__ bf16x8 ld8(const u16* p) {
    return __builtin_bit_cast(bf16x8, *reinterpret_cast<const u16x8*>(p));
}

// ---------------- K1: RMSNorm (fp32 in, bf16 out) ----------------
__global__ __launch_bounds__(256) void k_rmsnorm(const float* __restrict__ x,
                                                 const float* __restrict__ scale,
                                                 u16* __restrict__ h) {
    int row = blockIdx.x, tid = threadIdx.x;
    const float4* xr = reinterpret_cast<const float4*>(x + (size_t)row * 2048);
    float4 v0 = xr[tid], v1 = xr[tid + 256];
    float ss = v0.x*v0.x + v0.y*v0.y + v0.z*v0.z + v0.w*v0.w
             + v1.x*v1.x + v1.y*v1.y + v1.z*v1.z + v1.w*v1.w;
#pragma unroll
    for (int off = 32; off > 0; off >>= 1) ss += __shfl_down(ss, off, 64);
    __shared__ float red[4];
    if ((tid & 63) == 0) red[tid >> 6] = ss;
    __syncthreads();
    float r = rsqrtf((red[0] + red[1] + red[2] + red[3]) * (1.f / 2048.f) + 1e-6f);
    const float4* sc = reinterpret_cast<const float4*>(scale);
    float4 s0 = sc[tid], s1 = sc[tid + 256];
    ushort4 o0, o1;
    o0.x = f2bf(v0.x * r * s0.x); o0.y = f2bf(v0.y * r * s0.y);
    o0.z = f2bf(v0.z * r * s0.z); o0.w = f2bf(v0.w * r * s0.w);
    o1.x = f2bf(v1.x * r * s1.x); o1.y = f2bf(v1.y * r * s1.y);
    o1.z = f2bf(v1.z * r * s1.z); o1.w = f2bf(v1.w * r * s1.w);
    ushort4* hr = reinterpret_cast<ushort4*>(h + (size_t)row * 2048);
    hr[tid] = o0; hr[tid + 256] = o1;
}

// ---------------- K2/K8: MFMA GEMM. A bf16 MxK; B fp32 KxN converted on stage. ----------------
template <bool BF16_OUT>
__global__ __launch_bounds__(256) void k_gemm(const u16* __restrict__ A,
                                              const float* __restrict__ B,
                                              u16* __restrict__ Cb,
                                              float* __restrict__ Cf,
                                              const float* __restrict__ resid,
                                              int M, int N, int K) {
    __shared__ u16 As[64][40];
    __shared__ u16 Bs[64][40];
    int m0 = blockIdx.y * 64, n0 = blockIdx.x * 64;
    int tid = threadIdx.x, lane = tid & 63, w = tid >> 6;
    int wm = (w >> 1) * 32, wn = (w & 1) * 32;
    int r = lane & 15, q = lane >> 4;
    f32x4 acc[2][2];
#pragma unroll
    for (int a = 0; a < 2; ++a)
#pragma unroll
        for (int b = 0; b < 2; ++b) acc[a][b] = (f32x4){0.f, 0.f, 0.f, 0.f};

    int arow = tid >> 2, acol = (tid & 3) * 8;
    int bkrow = tid >> 3, bncol = (tid & 7) * 8;

    for (int k0 = 0; k0 < K; k0 += 32) {
        uint4 av = *reinterpret_cast<const uint4*>(A + (size_t)(m0 + arow) * K + k0 + acol);
        *reinterpret_cast<uint4*>(&As[arow][acol]) = av;
        int gn = n0 + bncol;
        u16 tmp[8];
        if (gn + 8 <= N) {
            const float4* bp = reinterpret_cast<const float4*>(B + (size_t)(k0 + bkrow) * N + gn);
            float4 b0 = bp[0], b1 = bp[1];
            tmp[0] = f2bf(b0.x); tmp[1] = f2bf(b0.y); tmp[2] = f2bf(b0.z); tmp[3] = f2bf(b0.w);
            tmp[4] = f2bf(b1.x); tmp[5] = f2bf(b1.y); tmp[6] = f2bf(b1.z); tmp[7] = f2bf(b1.w);
        } else {
#pragma unroll
            for (int i = 0; i < 8; ++i)
                tmp[i] = (gn + i < N) ? f2bf(B[(size_t)(k0 + bkrow) * N + gn + i]) : (u16)0;
        }
#pragma unroll
        for (int i = 0; i < 8; ++i) Bs[bncol + i][bkrow] = tmp[i];
        __syncthreads();

        bf16x8 a0 = ld8(&As[wm + r][q * 8]);
        bf16x8 a1 = ld8(&As[wm + 16 + r][q * 8]);
        bf16x8 b0 = ld8(&Bs[wn + r][q * 8]);
        bf16x8 b1 = ld8(&Bs[wn + 16 + r][q * 8]);
        acc[0][0] = __builtin_amdgcn_mfma_f32_16x16x32_bf16(a0, b0, acc[0][0], 0, 0, 0);
        acc[0][1] = __builtin_amdgcn_mfma_f32_16x16x32_bf16(a0, b1, acc[0][1], 0, 0, 0);
        acc[1][0] = __builtin_amdgcn_mfma_f32_16x16x32_bf16(a1, b0, acc[1][0], 0, 0, 0);
        acc[1][1] = __builtin_amdgcn_mfma_f32_16x16x32_bf16(a1, b1, acc[1][1], 0, 0, 0);
        __syncthreads();
    }
#pragma unroll
    for (int mt = 0; mt < 2; ++mt)
#pragma unroll
        for (int nt = 0; nt < 2; ++nt)
#pragma unroll
            for (int rg = 0; rg < 4; ++rg) {
                int gm = m0 + wm + mt * 16 + q * 4 + rg;
                int gn = n0 + wn + nt * 16 + r;
                if (gn < N) {
                    float vv = acc[mt][nt][rg];
                    if (BF16_OUT) {
                        Cb[(size_t)gm * N + gn] = f2bf(vv);
                    } else {
                        if (resid) vv += resid[(size_t)gm * N + gn];
                        Cf[(size_t)gm * N + gn] = vv;
                    }
                }
            }
}

// ---------------- K3: depthwise causal conv(4) + bias + SiLU ----------------
__global__ __launch_bounds__(256) void k_conv(const u16* __restrict__ proj,
                                              const float* __restrict__ cw,
                                              const float* __restrict__ cb,
                                              u16* __restrict__ xs) {
    int bt = blockIdx.x;
    int b = bt >> 11, t = bt & 2047;
    int tid = threadIdx.x;
#pragma unroll
    for (int i = 0; i < 16; ++i) {
        int ch = tid + i * 256;
        float acc = cb[ch];
#pragma unroll
        for (int k = 0; k < 4; ++k) {
            int tt = t - 3 + k;
            if (tt >= 0)
                acc += cw[k * 4096 + ch] * bf2f(proj[(size_t)(b * 2048 + tt) * 8480 + 4096 + ch]);
        }
        float s = acc / (1.f + expf(-acc));
        xs[(size_t)bt * 4096 + ch] = f2bf(s);
    }
}

// ---------------- K4: dt=softplus, per-chunk inclusive cumsum of A*dt ----------------
__global__ __launch_bounds__(64) void k_dt(const u16* __restrict__ proj,
                                           const float* __restrict__ A_log,
                                           const float* __restrict__ dt_bias,
                                           float* __restrict__ dt,
                                           float* __restrict__ cumla) {
    int bid = blockIdx.x;
    int b = bid >> 10, hh = (bid >> 5) & 31, c = bid & 31;
    int j = threadIdx.x;
    int t = c * 64 + j;
    float z = bf2f(proj[(size_t)(b * 2048 + t) * 8480 + 8192 + hh]) + dt_bias[hh];
    float dtv = (z > 20.f) ? z : log1pf(expf(z));
    float v = -expf(A_log[hh]) * dtv;
#pragma unroll
    for (int off = 1; off < 64; off <<= 1) {
        float pv = __shfl_up(v, off, 64);
        if (j >= off) v += pv;
    }
    int base = ((b * 32 + hh) * 32 + c) * 64;
    dt[base + j] = dtv;
    cumla[base + j] = v;
}

// ---------------- K5: intra-chunk (MFMA): M=decay(C·B^T), Y=M·X, St=X^T·Bw ----------------
__global__ __launch_bounds__(256) void k_intra(const u16* __restrict__ proj,
                                               const u16* __restrict__ xs,
                                               const float* __restrict__ dt,
                                               const float* __restrict__ cumla,
                                               u16* __restrict__ ybuf,
                                               u16* __restrict__ states) {
    __shared__ u16 Cs[64][136];   // C rows   (A-op step1)      272B stride, 16B-aligned
    __shared__ u16 Bs[64][136];   // B rows   (B-op step1)
    __shared__ u16 Xt[128][72];   // X^T      (B-op step2, A-op step3) 144B stride
    __shared__ u16 Bt[128][72];   // w_j*B^T  (B-op step3)
    __shared__ u16 Ms[64][72];    // M bf16   (A-op step2)
    __shared__ float dts[64], clas[64];
    int bid = blockIdx.x;
    int b = bid >> 10, c = (bid >> 5) & 31, hh = bid & 31;
    int tid = threadIdx.x, lane = tid & 63, w = tid >> 6;
    int r = lane & 15, q = lane >> 4;
    int t0 = b * 2048 + c * 64;
    int sbase = ((b * 32 + hh) * 32 + c) * 64;

    if (tid < 64) { dts[tid] = dt[sbase + tid]; clas[tid] = cumla[sbase + tid]; }

    // stage C,B rows (coalesced uint4)
    for (int e = tid; e < 1024; e += 256) {
        int i = e >> 4, n8 = (e & 15) * 8;
        size_t rp = (size_t)(t0 + i) * 8480;
        *reinterpret_cast<uint4*>(&Cs[i][n8]) = *reinterpret_cast<const uint4*>(proj + rp + 8352 + n8);
        *reinterpret_cast<uint4*>(&Bs[i][n8]) = *reinterpret_cast<const uint4*>(proj + rp + 8224 + n8);
    }
    // transpose-stage Xt and weighted Bt (j = lane; LDS writes contiguous across lanes)
    {
        int j = lane + (w & 1) * 0;          // j = tid & 63
        j = tid & 63;
        float wj = expf(cumla[sbase + 63] - cumla[sbase + j]) * dt[sbase + j];
        for (int g = tid >> 6; g < 16; g += 4) {
            int p0 = g * 8;
            u16 tx[8], tb[8];
            *reinterpret_cast<uint4*>(tx) = *reinterpret_cast<const uint4*>(xs + (size_t)(t0 + j) * 4096 + hh * 128 + p0);
            *reinterpret_cast<uint4*>(tb) = *reinterpret_cast<const uint4*>(proj + (size_t)(t0 + j) * 8480 + 8224 + p0);
#pragma unroll
            for (int k = 0; k < 8; ++k) {
                Xt[p0 + k][j] = tx[k];
                Bt[p0 + k][j] = f2bf(wj * bf2f(tb[k]));
            }
        }
    }
    __syncthreads();

    // ---- step 1: CB tile-strip ti=w; write masked/decayed M ----
    {
        bf16x8 af[4];
#pragma unroll
        for (int k = 0; k < 4; ++k) af[k] = ld8(&Cs[w * 16 + r][k * 32 + q * 8]);
#pragma unroll
        for (int tj = 0; tj < 4; ++tj) {
            f32x4 acc = (f32x4){0.f, 0.f, 0.f, 0.f};
#pragma unroll
            for (int k = 0; k < 4; ++k)
                acc = __builtin_amdgcn_mfma_f32_16x16x32_bf16(af[k], ld8(&Bs[tj * 16 + r][k * 32 + q * 8]), acc, 0, 0, 0);
            int j = tj * 16 + r;
            float dj = dts[j], cj = clas[j];
#pragma unroll
            for (int rg = 0; rg < 4; ++rg) {
                int i = w * 16 + q * 4 + rg;
                float m = (j <= i) ? acc[rg] * expf(clas[i] - cj) * dj : 0.f;
                Ms[i][j] = f2bf(m);
            }
        }
    }
    __syncthreads();

    // ---- step 2: Y = M @ X  (row-strip ti=w), K=64 ----
    {
        bf16x8 af[2];
#pragma unroll
        for (int k = 0; k < 2; ++k) af[k] = ld8(&Ms[w * 16 + r][k * 32 + q * 8]);
#pragma unroll
        for (int tj = 0; tj < 8; ++tj) {
            f32x4 acc = (f32x4){0.f, 0.f, 0.f, 0.f};
#pragma unroll
            for (int k = 0; k < 2; ++k)
                acc = __builtin_amdgcn_mfma_f32_16x16x32_bf16(af[k], ld8(&Xt[tj * 16 + r][k * 32 + q * 8]), acc, 0, 0, 0);
            int p = tj * 16 + r;
#pragma unroll
            for (int rg = 0; rg < 4; ++rg) {
                int i = w * 16 + q * 4 + rg;
                ybuf[(size_t)(t0 + i) * 4096 + hh * 128 + p] = f2bf(acc[rg]);
            }
        }
    }

    // ---- step 3: St[p][n] = sum_j Xt[p][j] * Bt[n][j]  (strips ti=w, w+4), K=64 ----
    size_t sb = ((size_t)((b * 32 + hh) * 32 + c)) * 16384;
#pragma unroll
    for (int th = 0; th < 2; ++th) {
        int ti = w + th * 4;
        bf16x8 af[2];
#pragma unroll
        for (int k = 0; k < 2; ++k) af[k] = ld8(&Xt[ti * 16 + r][k * 32 + q * 8]);
#pragma unroll
        for (int tj = 0; tj < 8; ++tj) {
            f32x4 acc = (f32x4){0.f, 0.f, 0.f, 0.f};
#pragma unroll
            for (int k = 0; k < 2; ++k)
                acc = __builtin_amdgcn_mfma_f32_16x16x32_bf16(af[k], ld8(&Bt[tj * 16 + r][k * 32 + q * 8]), acc, 0, 0, 0);
            int n = tj * 16 + r;
#pragma unroll
            for (int rg = 0; rg < 4; ++rg) {
                int p = ti * 16 + q * 4 + rg;
                states[sb + p * 128 + n] = f2bf(acc[rg]);
            }
        }
    }
}

// ---------------- K6: inter-chunk sequential scan (elementwise over [p][n]) ----------------
__global__ __launch_bounds__(256) void k_scan(u16* __restrict__ states,
                                              const float* __restrict__ cumla) {
    int gid = blockIdx.x * 256 + threadIdx.x;
    int bh = gid >> 14;
    int np = gid & 16383;
    size_t base = (size_t)bh * 32 * 16384 + np;
    float s = 0.f;
    for (int c = 0; c < 32; ++c) {
        float cd = expf(cumla[(bh * 32 + c) * 64 + 63]);
        size_t idx = base + (size_t)c * 16384;
        float loc = bf2f(states[idx]);
        states[idx] = f2bf(s);
        s = cd * s + loc;
    }
}

// ---------------- K7: Y += exp(cla)*C@S + D*x, SiLU gate (MFMA) ----------------
__global__ __launch_bounds__(256) void k_inter(const u16* __restrict__ proj,
                                               const u16* __restrict__ xs,
                                               const u16* __restrict__ states,
                                               const float* __restrict__ cumla,
                                               const u16* __restrict__ ybuf,
                                               const float* __restrict__ Dv,
                                               u16* __restrict__ ygated) {
    __shared__ u16 Cs[64][136];    // C rows (A-op)
    __shared__ u16 Ss[128][136];   // St rows [p][n] (B-op)
    __shared__ float clav[64];
    int bid = blockIdx.x;
    int b = bid >> 10, c = (bid >> 5) & 31, hh = bid & 31;
    int tid = threadIdx.x, lane = tid & 63, w = tid >> 6;
    int r = lane & 15, q = lane >> 4;
    int t0 = b * 2048 + c * 64;
    int sbase = ((b * 32 + hh) * 32 + c) * 64;
    size_t sb = ((size_t)((b * 32 + hh) * 32 + c)) * 16384;

    if (tid < 64) clav[tid] = expf(cumla[sbase + tid]);
    for (int e = tid; e < 1024; e += 256) {
        int i = e >> 4, n8 = (e & 15) * 8;
        *reinterpret_cast<uint4*>(&Cs[i][n8]) =
            *reinterpret_cast<const uint4*>(proj + (size_t)(t0 + i) * 8480 + 8352 + n8);
    }
    for (int e = tid; e < 2048; e += 256) {
        int p = e >> 4, n8 = (e & 15) * 8;
        *reinterpret_cast<uint4*>(&Ss[p][n8]) =
            *reinterpret_cast<const uint4*>(states + sb + p * 128 + n8);
    }
    __syncthreads();

    bf16x8 af[4];
#pragma unroll
    for (int k = 0; k < 4; ++k) af[k] = ld8(&Cs[w * 16 + r][k * 32 + q * 8]);
#pragma unroll
    for (int tj = 0; tj < 8; ++tj) {
        f32x4 acc = (f32x4){0.f, 0.f, 0.f, 0.f};
#pragma unroll
        for (int k = 0; k < 4; ++k)
            acc = __builtin_amdgcn_mfma_f32_16x16x32_bf16(af[k], ld8(&Ss[tj * 16 + r][k * 32 + q * 8]), acc, 0, 0, 0);
        int p = tj * 16 + r;
        int ch = hh * 128 + p;
        float dv = Dv[ch];
#pragma unroll
        for (int rg = 0; rg < 4; ++rg) {
            int i = w * 16 + q * 4 + rg;
            size_t td = (size_t)(t0 + i) * 4096 + ch;
            float v = clav[i] * acc[rg] + bf2f(ybuf[td]) + dv * bf2f(xs[td]);
            float g = bf2f(proj[(size_t)(t0 + i) * 8480 + ch]);
            ygated[td] = f2bf(v * (g / (1.f + expf(-g))));
        }
    }
}

extern "C" void kernel_launch(void* const* d_in, const int* in_sizes, int n_in,
                              void* d_out, int out_size, void* d_ws, size_t ws_size,
                              hipStream_t stream) {
    const float* x          = (const float*)d_in[0];
    const float* norm_scale = (const float*)d_in[1];
    const float* in_proj_w  = (const float*)d_in[2];
    const float* conv_w     = (const float*)d_in[3];
    const float* conv_b     = (const float*)d_in[4];
    const float* A_log      = (const float*)d_in[5];
    const float* dt_bias    = (const float*)d_in[6];
    const float* Dv         = (const float*)d_in[7];
    const float* out_w      = (const float*)d_in[8];
    float* out = (float*)d_out;

    char* ws = (char*)d_ws;
    u16*   states = (u16*)(ws);               // 67,108,864 ; h aliases head (dead early)
    u16*   h      = (u16*)(ws);
    u16*   proj   = (u16*)(ws + 67108864);    // 69,468,160
    u16*   xs     = (u16*)(ws + 136577024);   // 33,554,432
    u16*   ybuf   = (u16*)(ws + 170131456);   // 33,554,432 (also ygated)
    float* dt     = (float*)(ws + 203685888); // 524,288
    float* cumla  = (float*)(ws + 204210176); // 524,288

    k_rmsnorm<<<4096, 256, 0, stream>>>(x, norm_scale, h);
    k_gemm<true><<<dim3(133, 64), 256, 0, stream>>>(h, in_proj_w, proj, nullptr, nullptr, 4096, 8480, 2048);
    k_conv<<<4096, 256, 0, stream>>>(proj, conv_w, conv_b, xs);
    k_dt<<<2048, 64, 0, stream>>>(proj, A_log, dt_bias, dt, cumla);
    k_intra<<<2048, 256, 0, stream>>>(proj, xs, dt, cumla, ybuf, states);
    k_scan<<<4096, 256, 0, stream>>>(states, cumla);
    k_inter<<<2048, 256, 0, stream>>>(proj, xs, states, cumla, ybuf, Dv, ybuf);
    k_gemm<false><<<dim3(32, 64), 256, 0, stream>>>(ybuf, out_w, nullptr, out, x, 4096, 2048, 4096);
}

// Round 4
// 702.290 us; speedup vs baseline: 3.4979x; 1.8884x over previous
//
#include <hip/hip_runtime.h>

typedef unsigned short u16;
typedef unsigned short u16x8 __attribute__((ext_vector_type(8)));
typedef __bf16 bf16x8 __attribute__((ext_vector_type(8)));
typedef float f32x4 __attribute__((ext_vector_type(4)));

// B=2, T=2048, N_EMBD=2048, D_INNER=4096, N_HEADS=32, HEAD_DIM=128, D_STATE=128,
// PROJ=8480 (pad 8576), CHUNK=64, n_chunks=32. External tensors FP32; staging bf16.
// proj row: [0,4096) gate | [4096,8192) ssm_in | [8192,8224) dt | [8224,8352) B | [8352,8480) C

__device__ __forceinline__ float bf2f(u16 u) {
    union { unsigned int i; float f; } v; v.i = ((unsigned int)u) << 16; return v.f;
}
__device__ __forceinline__ u16 f2bf(float f) {
    unsigned int u = __float_as_uint(f);
    u += 0x7fffu + ((u >> 16) & 1u);   // RNE
    return (u16)(u >> 16);
}
__device__ __forceinline__ bf16x8 ld8(const u16* p) {
    return __builtin_bit_cast(bf16x8, *reinterpret_cast<const u16x8*>(p));
}
// async global->LDS, 16B per lane; lds base must be wave-uniform (lane scatter implicit)
__device__ __forceinline__ void load_lds16(const u16* g, u16* l) {
    __builtin_amdgcn_global_load_lds(
        (const __attribute__((address_space(1))) unsigned int*)g,
        (__attribute__((address_space(3))) unsigned int*)l, 16, 0, 0);
}

// ---------------- K1: RMSNorm (fp32 in, bf16 out) ----------------
__global__ __launch_bounds__(256) void k_rmsnorm(const float* __restrict__ x,
                                                 const float* __restrict__ scale,
                                                 u16* __restrict__ h) {
    int row = blockIdx.x, tid = threadIdx.x;
    const float4* xr = reinterpret_cast<const float4*>(x + (size_t)row * 2048);
    float4 v0 = xr[tid], v1 = xr[tid + 256];
    float ss = v0.x*v0.x + v0.y*v0.y + v0.z*v0.z + v0.w*v0.w
             + v1.x*v1.x + v1.y*v1.y + v1.z*v1.z + v1.w*v1.w;
#pragma unroll
    for (int off = 32; off > 0; off >>= 1) ss += __shfl_down(ss, off, 64);
    __shared__ float red[4];
    if ((tid & 63) == 0) red[tid >> 6] = ss;
    __syncthreads();
    float r = rsqrtf((red[0] + red[1] + red[2] + red[3]) * (1.f / 2048.f) + 1e-6f);
    const float4* sc = reinterpret_cast<const float4*>(scale);
    float4 s0 = sc[tid], s1 = sc[tid + 256];
    ushort4 o0, o1;
    o0.x = f2bf(v0.x * r * s0.x); o0.y = f2bf(v0.y * r * s0.y);
    o0.z = f2bf(v0.z * r * s0.z); o0.w = f2bf(v0.w * r * s0.w);
    o1.x = f2bf(v1.x * r * s1.x); o1.y = f2bf(v1.y * r * s1.y);
    o1.z = f2bf(v1.z * r * s1.z); o1.w = f2bf(v1.w * r * s1.w);
    ushort4* hr = reinterpret_cast<ushort4*>(h + (size_t)row * 2048);
    hr[tid] = o0; hr[tid + 256] = o1;
}

// ---------------- K0: transpose-cast weights fp32 [K][N] -> bf16 [Npad][K], zero-pad ----------------
__global__ __launch_bounds__(256) void k_wcast(const float* __restrict__ W,
                                               u16* __restrict__ Wt,
                                               int K, int N) {
    __shared__ u16 Ts[64][72];
    int n0 = blockIdx.x * 64, k0 = blockIdx.y * 64;
    int t = threadIdx.x;
    int jl = (t & 15) * 4;
#pragma unroll
    for (int s = 0; s < 4; ++s) {
        int kl = s * 16 + (t >> 4);
        if (n0 + jl + 4 <= N) {
            float4 v = *reinterpret_cast<const float4*>(W + (size_t)(k0 + kl) * N + n0 + jl);
            Ts[kl][jl] = f2bf(v.x); Ts[kl][jl + 1] = f2bf(v.y);
            Ts[kl][jl + 2] = f2bf(v.z); Ts[kl][jl + 3] = f2bf(v.w);
        } else {
#pragma unroll
            for (int e = 0; e < 4; ++e)
                Ts[kl][jl + e] = (n0 + jl + e < N) ? f2bf(W[(size_t)(k0 + kl) * N + n0 + jl + e]) : (u16)0;
        }
    }
    __syncthreads();
    int nl = t >> 2, kl0 = (t & 3) * 16;
    u16 tmp[16];
#pragma unroll
    for (int e = 0; e < 16; ++e) tmp[e] = Ts[kl0 + e][nl];
    u16* dst = Wt + (size_t)(n0 + nl) * K + k0 + kl0;
    *reinterpret_cast<uint4*>(dst) = *reinterpret_cast<uint4*>(tmp);
    *reinterpret_cast<uint4*>(dst + 8) = *reinterpret_cast<uint4*>(tmp + 8);
}

// ---------------- K2/K8: 128x128 MFMA GEMM (m97 structure), A bf16 [M][K], Bt bf16 [Npad][K] ----------------
template <bool BF16_OUT>
__global__ __launch_bounds__(256) void k_gemm128(const u16* __restrict__ A,
                                                 const u16* __restrict__ Bt,
                                                 u16* __restrict__ Cb,
                                                 float* __restrict__ Cf,
                                                 const float* __restrict__ resid,
                                                 int M, int Nout, int K) {
    __shared__ u16 As[128 * 32];   // [m][k], contiguous (global_load_lds lane order)
    __shared__ u16 Bs[128 * 32];   // [n][k]
    int m0 = blockIdx.y * 128, n0 = blockIdx.x * 128;
    int t = threadIdx.x, lane = t & 63, w = t >> 6;
    int row = t >> 2, kc = (t & 3) * 8;
    int wm = (w >> 1) * 64, wn = (w & 1) * 64;
    int r = lane & 15, q = lane >> 4;

    f32x4 acc[4][4];
#pragma unroll
    for (int a = 0; a < 4; ++a)
#pragma unroll
        for (int b = 0; b < 4; ++b) acc[a][b] = (f32x4){0.f, 0.f, 0.f, 0.f};

    const u16* ga0 = A + (size_t)(m0 + row) * K + kc;
    const u16* ga1 = A + (size_t)(m0 + 64 + row) * K + kc;
    const u16* gb0 = Bt + (size_t)(n0 + row) * K + kc;
    const u16* gb1 = Bt + (size_t)(n0 + 64 + row) * K + kc;

    for (int k0 = 0; k0 < K; k0 += 32) {
        load_lds16(ga0 + k0, As + w * 512);
        load_lds16(ga1 + k0, As + 2048 + w * 512);
        load_lds16(gb0 + k0, Bs + w * 512);
        load_lds16(gb1 + k0, Bs + 2048 + w * 512);
        __syncthreads();

        bf16x8 af[4], bf[4];
#pragma unroll
        for (int mi = 0; mi < 4; ++mi) af[mi] = ld8(&As[(wm + mi * 16 + r) * 32 + q * 8]);
#pragma unroll
        for (int ni = 0; ni < 4; ++ni) bf[ni] = ld8(&Bs[(wn + ni * 16 + r) * 32 + q * 8]);
#pragma unroll
        for (int mi = 0; mi < 4; ++mi)
#pragma unroll
            for (int ni = 0; ni < 4; ++ni)
                acc[mi][ni] = __builtin_amdgcn_mfma_f32_16x16x32_bf16(af[mi], bf[ni], acc[mi][ni], 0, 0, 0);
        __syncthreads();
    }
    // C/D: col = lane&15, row = (lane>>4)*4 + reg
#pragma unroll
    for (int mi = 0; mi < 4; ++mi)
#pragma unroll
        for (int ni = 0; ni < 4; ++ni) {
            int gn = n0 + wn + ni * 16 + r;
            if (gn < Nout) {
#pragma unroll
                for (int rg = 0; rg < 4; ++rg) {
                    int gm = m0 + wm + mi * 16 + q * 4 + rg;
                    float vv = acc[mi][ni][rg];
                    if (BF16_OUT) {
                        Cb[(size_t)gm * Nout + gn] = f2bf(vv);
                    } else {
                        if (resid) vv += resid[(size_t)gm * Nout + gn];
                        Cf[(size_t)gm * Nout + gn] = vv;
                    }
                }
            }
        }
}

// ---------------- K3: depthwise causal conv(4) + bias + SiLU ----------------
__global__ __launch_bounds__(256) void k_conv(const u16* __restrict__ proj,
                                              const float* __restrict__ cw,
                                              const float* __restrict__ cb,
                                              u16* __restrict__ xs) {
    int bt = blockIdx.x;
    int b = bt >> 11, t = bt & 2047;
    int tid = threadIdx.x;
#pragma unroll
    for (int i = 0; i < 16; ++i) {
        int ch = tid + i * 256;
        float acc = cb[ch];
#pragma unroll
        for (int k = 0; k < 4; ++k) {
            int tt = t - 3 + k;
            if (tt >= 0)
                acc += cw[k * 4096 + ch] * bf2f(proj[(size_t)(b * 2048 + tt) * 8480 + 4096 + ch]);
        }
        float s = acc / (1.f + expf(-acc));
        xs[(size_t)bt * 4096 + ch] = f2bf(s);
    }
}

// ---------------- K4: dt=softplus, per-chunk inclusive cumsum of A*dt ----------------
__global__ __launch_bounds__(64) void k_dt(const u16* __restrict__ proj,
                                           const float* __restrict__ A_log,
                                           const float* __restrict__ dt_bias,
                                           float* __restrict__ dt,
                                           float* __restrict__ cumla) {
    int bid = blockIdx.x;
    int b = bid >> 10, hh = (bid >> 5) & 31, c = bid & 31;
    int j = threadIdx.x;
    int t = c * 64 + j;
    float z = bf2f(proj[(size_t)(b * 2048 + t) * 8480 + 8192 + hh]) + dt_bias[hh];
    float dtv = (z > 20.f) ? z : log1pf(expf(z));
    float v = -expf(A_log[hh]) * dtv;
#pragma unroll
    for (int off = 1; off < 64; off <<= 1) {
        float pv = __shfl_up(v, off, 64);
        if (j >= off) v += pv;
    }
    int base = ((b * 32 + hh) * 32 + c) * 64;
    dt[base + j] = dtv;
    cumla[base + j] = v;
}

// ---------------- K5: intra-chunk (MFMA): M=decay(C·B^T), Y=M·X, St=X^T·Bw ----------------
__global__ __launch_bounds__(256) void k_intra(const u16* __restrict__ proj,
                                               const u16* __restrict__ xs,
                                               const float* __restrict__ dt,
                                               const float* __restrict__ cumla,
                                               u16* __restrict__ ybuf,
                                               u16* __restrict__ states) {
    __shared__ u16 Cs[64][136];
    __shared__ u16 Bs[64][136];
    __shared__ u16 Xt[128][72];
    __shared__ u16 Bt[128][72];
    __shared__ u16 Ms[64][72];
    __shared__ float dts[64], clas[64];
    int bid = blockIdx.x;
    int b = bid >> 10, c = (bid >> 5) & 31, hh = bid & 31;
    int tid = threadIdx.x, lane = tid & 63, w = tid >> 6;
    int r = lane & 15, q = lane >> 4;
    int t0 = b * 2048 + c * 64;
    int sbase = ((b * 32 + hh) * 32 + c) * 64;

    if (tid < 64) { dts[tid] = dt[sbase + tid]; clas[tid] = cumla[sbase + tid]; }

    for (int e = tid; e < 1024; e += 256) {
        int i = e >> 4, n8 = (e & 15) * 8;
        size_t rp = (size_t)(t0 + i) * 8480;
        *reinterpret_cast<uint4*>(&Cs[i][n8]) = *reinterpret_cast<const uint4*>(proj + rp + 8352 + n8);
        *reinterpret_cast<uint4*>(&Bs[i][n8]) = *reinterpret_cast<const uint4*>(proj + rp + 8224 + n8);
    }
    {
        int j = tid & 63;
        float wj = expf(cumla[sbase + 63] - cumla[sbase + j]) * dt[sbase + j];
        for (int g = tid >> 6; g < 16; g += 4) {
            int p0 = g * 8;
            u16 tx[8], tb[8];
            *reinterpret_cast<uint4*>(tx) = *reinterpret_cast<const uint4*>(xs + (size_t)(t0 + j) * 4096 + hh * 128 + p0);
            *reinterpret_cast<uint4*>(tb) = *reinterpret_cast<const uint4*>(proj + (size_t)(t0 + j) * 8480 + 8224 + p0);
#pragma unroll
            for (int k = 0; k < 8; ++k) {
                Xt[p0 + k][j] = tx[k];
                Bt[p0 + k][j] = f2bf(wj * bf2f(tb[k]));
            }
        }
    }
    __syncthreads();

    {
        bf16x8 af[4];
#pragma unroll
        for (int k = 0; k < 4; ++k) af[k] = ld8(&Cs[w * 16 + r][k * 32 + q * 8]);
#pragma unroll
        for (int tj = 0; tj < 4; ++tj) {
            f32x4 acc = (f32x4){0.f, 0.f, 0.f, 0.f};
#pragma unroll
            for (int k = 0; k < 4; ++k)
                acc = __builtin_amdgcn_mfma_f32_16x16x32_bf16(af[k], ld8(&Bs[tj * 16 + r][k * 32 + q * 8]), acc, 0, 0, 0);
            int j = tj * 16 + r;
            float dj = dts[j], cj = clas[j];
#pragma unroll
            for (int rg = 0; rg < 4; ++rg) {
                int i = w * 16 + q * 4 + rg;
                float m = (j <= i) ? acc[rg] * expf(clas[i] - cj) * dj : 0.f;
                Ms[i][j] = f2bf(m);
            }
        }
    }
    __syncthreads();

    {
        bf16x8 af[2];
#pragma unroll
        for (int k = 0; k < 2; ++k) af[k] = ld8(&Ms[w * 16 + r][k * 32 + q * 8]);
#pragma unroll
        for (int tj = 0; tj < 8; ++tj) {
            f32x4 acc = (f32x4){0.f, 0.f, 0.f, 0.f};
#pragma unroll
            for (int k = 0; k < 2; ++k)
                acc = __builtin_amdgcn_mfma_f32_16x16x32_bf16(af[k], ld8(&Xt[tj * 16 + r][k * 32 + q * 8]), acc, 0, 0, 0);
            int p = tj * 16 + r;
#pragma unroll
            for (int rg = 0; rg < 4; ++rg) {
                int i = w * 16 + q * 4 + rg;
                ybuf[(size_t)(t0 + i) * 4096 + hh * 128 + p] = f2bf(acc[rg]);
            }
        }
    }

    size_t sb = ((size_t)((b * 32 + hh) * 32 + c)) * 16384;
#pragma unroll
    for (int th = 0; th < 2; ++th) {
        int ti = w + th * 4;
        bf16x8 af[2];
#pragma unroll
        for (int k = 0; k < 2; ++k) af[k] = ld8(&Xt[ti * 16 + r][k * 32 + q * 8]);
#pragma unroll
        for (int tj = 0; tj < 8; ++tj) {
            f32x4 acc = (f32x4){0.f, 0.f, 0.f, 0.f};
#pragma unroll
            for (int k = 0; k < 2; ++k)
                acc = __builtin_amdgcn_mfma_f32_16x16x32_bf16(af[k], ld8(&Bt[tj * 16 + r][k * 32 + q * 8]), acc, 0, 0, 0);
            int n = tj * 16 + r;
#pragma unroll
            for (int rg = 0; rg < 4; ++rg) {
                int p = ti * 16 + q * 4 + rg;
                states[sb + p * 128 + n] = f2bf(acc[rg]);
            }
        }
    }
}

// ---------------- K6: inter-chunk sequential scan ----------------
__global__ __launch_bounds__(256) void k_scan(u16* __restrict__ states,
                                              const float* __restrict__ cumla) {
    int gid = blockIdx.x * 256 + threadIdx.x;
    int bh = gid >> 14;
    int np = gid & 16383;
    size_t base = (size_t)bh * 32 * 16384 + np;
    float s = 0.f;
    for (int c = 0; c < 32; ++c) {
        float cd = expf(cumla[(bh * 32 + c) * 64 + 63]);
        size_t idx = base + (size_t)c * 16384;
        float loc = bf2f(states[idx]);
        states[idx] = f2bf(s);
        s = cd * s + loc;
    }
}

// ---------------- K7: Y += exp(cla)*C@S + D*x, SiLU gate (MFMA) ----------------
__global__ __launch_bounds__(256) void k_inter(const u16* __restrict__ proj,
                                               const u16* __restrict__ xs,
                                               const u16* __restrict__ states,
                                               const float* __restrict__ cumla,
                                               const u16* __restrict__ ybuf,
                                               const float* __restrict__ Dv,
                                               u16* __restrict__ ygated) {
    __shared__ u16 Cs[64][136];
    __shared__ u16 Ss[128][136];
    __shared__ float clav[64];
    int bid = blockIdx.x;
    int b = bid >> 10, c = (bid >> 5) & 31, hh = bid & 31;
    int tid = threadIdx.x, lane = tid & 63, w = tid >> 6;
    int r = lane & 15, q = lane >> 4;
    int t0 = b * 2048 + c * 64;
    int sbase = ((b * 32 + hh) * 32 + c) * 64;
    size_t sb = ((size_t)((b * 32 + hh) * 32 + c)) * 16384;

    if (tid < 64) clav[tid] = expf(cumla[sbase + tid]);
    for (int e = tid; e < 1024; e += 256) {
        int i = e >> 4, n8 = (e & 15) * 8;
        *reinterpret_cast<uint4*>(&Cs[i][n8]) =
            *reinterpret_cast<const uint4*>(proj + (size_t)(t0 + i) * 8480 + 8352 + n8);
    }
    for (int e = tid; e < 2048; e += 256) {
        int p = e >> 4, n8 = (e & 15) * 8;
        *reinterpret_cast<uint4*>(&Ss[p][n8]) =
            *reinterpret_cast<const uint4*>(states + sb + p * 128 + n8);
    }
    __syncthreads();

    bf16x8 af[4];
#pragma unroll
    for (int k = 0; k < 4; ++k) af[k] = ld8(&Cs[w * 16 + r][k * 32 + q * 8]);
#pragma unroll
    for (int tj = 0; tj < 8; ++tj) {
        f32x4 acc = (f32x4){0.f, 0.f, 0.f, 0.f};
#pragma unroll
        for (int k = 0; k < 4; ++k)
            acc = __builtin_amdgcn_mfma_f32_16x16x32_bf16(af[k], ld8(&Ss[tj * 16 + r][k * 32 + q * 8]), acc, 0, 0, 0);
        int p = tj * 16 + r;
        int ch = hh * 128 + p;
        float dv = Dv[ch];
#pragma unroll
        for (int rg = 0; rg < 4; ++rg) {
            int i = w * 16 + q * 4 + rg;
            size_t td = (size_t)(t0 + i) * 4096 + ch;
            float v = clav[i] * acc[rg] + bf2f(ybuf[td]) + dv * bf2f(xs[td]);
            float g = bf2f(proj[(size_t)(t0 + i) * 8480 + ch]);
            ygated[td] = f2bf(v * (g / (1.f + expf(-g))));
        }
    }
}

extern "C" void kernel_launch(void* const* d_in, const int* in_sizes, int n_in,
                              void* d_out, int out_size, void* d_ws, size_t ws_size,
                              hipStream_t stream) {
    const float* x          = (const float*)d_in[0];
    const float* norm_scale = (const float*)d_in[1];
    const float* in_proj_w  = (const float*)d_in[2];
    const float* conv_w     = (const float*)d_in[3];
    const float* conv_b     = (const float*)d_in[4];
    const float* A_log      = (const float*)d_in[5];
    const float* dt_bias    = (const float*)d_in[6];
    const float* Dv         = (const float*)d_in[7];
    const float* out_w      = (const float*)d_in[8];
    float* out = (float*)d_out;

    char* ws = (char*)d_ws;
    // region [0, 67,108,864): states. h aliases [0, 16.8M) (dead before k_intra);
    // wbt aliases [16.8M, 51.9M) (dead after in_proj gemm, before k_intra).
    u16*   states = (u16*)(ws);
    u16*   h      = (u16*)(ws);
    u16*   wbt    = (u16*)(ws + 16777216);    // 8576x2048 bf16 = 35,127,296
    u16*   proj   = (u16*)(ws + 67108864);    // 69,468,160
    u16*   xs     = (u16*)(ws + 136577024);   // 33,554,432 ; owt aliases (xs dead after k_inter)
    u16*   owt    = (u16*)(ws + 136577024);   // 2048x4096 bf16 = 16,777,216
    u16*   ybuf   = (u16*)(ws + 170131456);   // 33,554,432 (also ygated)
    float* dt     = (float*)(ws + 203685888); // 524,288
    float* cumla  = (float*)(ws + 204210176); // 524,288

    k_rmsnorm<<<4096, 256, 0, stream>>>(x, norm_scale, h);
    k_wcast<<<dim3(134, 32), 256, 0, stream>>>(in_proj_w, wbt, 2048, 8480);
    k_gemm128<true><<<dim3(67, 32), 256, 0, stream>>>(h, wbt, proj, nullptr, nullptr, 4096, 8480, 2048);
    k_conv<<<4096, 256, 0, stream>>>(proj, conv_w, conv_b, xs);
    k_dt<<<2048, 64, 0, stream>>>(proj, A_log, dt_bias, dt, cumla);
    k_intra<<<2048, 256, 0, stream>>>(proj, xs, dt, cumla, ybuf, states);
    k_scan<<<4096, 256, 0, stream>>>(states, cumla);
    k_inter<<<2048, 256, 0, stream>>>(proj, xs, states, cumla, ybuf, Dv, ybuf);
    k_wcast<<<dim3(32, 64), 256, 0, stream>>>(out_w, owt, 4096, 2048);
    k_gemm128<false><<<dim3(16, 32), 256, 0, stream>>>(ybuf, owt, nullptr, out, x, 4096, 2048, 4096);
}

// Round 5
// 597.121 us; speedup vs baseline: 4.1140x; 1.1761x over previous
//
#include <hip/hip_runtime.h>

typedef unsigned short u16;
typedef unsigned short u16x8 __attribute__((ext_vector_type(8)));
typedef __bf16 bf16x8 __attribute__((ext_vector_type(8)));
typedef float f32x4 __attribute__((ext_vector_type(4)));

// B=2, T=2048, N_EMBD=2048, D_INNER=4096, N_HEADS=32, HEAD_DIM=128, D_STATE=128,
// PROJ=8480 (pad 8576), CHUNK=64, n_chunks=32. External tensors FP32; staging bf16.
// proj row: [0,4096) gate | [4096,8192) ssm_in | [8192,8224) dt | [8224,8352) B | [8352,8480) C

__device__ __forceinline__ float bf2f(u16 u) {
    union { unsigned int i; float f; } v; v.i = ((unsigned int)u) << 16; return v.f;
}
__device__ __forceinline__ u16 f2bf(float f) {
    unsigned int u = __float_as_uint(f);
    u += 0x7fffu + ((u >> 16) & 1u);   // RNE
    return (u16)(u >> 16);
}
__device__ __forceinline__ bf16x8 ld8(const u16* p) {
    return __builtin_bit_cast(bf16x8, *reinterpret_cast<const u16x8*>(p));
}
__device__ __forceinline__ void load_lds16(const u16* g, u16* l) {
    __builtin_amdgcn_global_load_lds(
        (const __attribute__((address_space(1))) unsigned int*)g,
        (__attribute__((address_space(3))) unsigned int*)l, 16, 0, 0);
}

// ---------------- K1: RMSNorm (fp32 in, bf16 out) ----------------
__global__ __launch_bounds__(256) void k_rmsnorm(const float* __restrict__ x,
                                                 const float* __restrict__ scale,
                                                 u16* __restrict__ h) {
    int row = blockIdx.x, tid = threadIdx.x;
    const float4* xr = reinterpret_cast<const float4*>(x + (size_t)row * 2048);
    float4 v0 = xr[tid], v1 = xr[tid + 256];
    float ss = v0.x*v0.x + v0.y*v0.y + v0.z*v0.z + v0.w*v0.w
             + v1.x*v1.x + v1.y*v1.y + v1.z*v1.z + v1.w*v1.w;
#pragma unroll
    for (int off = 32; off > 0; off >>= 1) ss += __shfl_down(ss, off, 64);
    __shared__ float red[4];
    if ((tid & 63) == 0) red[tid >> 6] = ss;
    __syncthreads();
    float r = rsqrtf((red[0] + red[1] + red[2] + red[3]) * (1.f / 2048.f) + 1e-6f);
    const float4* sc = reinterpret_cast<const float4*>(scale);
    float4 s0 = sc[tid], s1 = sc[tid + 256];
    ushort4 o0, o1;
    o0.x = f2bf(v0.x * r * s0.x); o0.y = f2bf(v0.y * r * s0.y);
    o0.z = f2bf(v0.z * r * s0.z); o0.w = f2bf(v0.w * r * s0.w);
    o1.x = f2bf(v1.x * r * s1.x); o1.y = f2bf(v1.y * r * s1.y);
    o1.z = f2bf(v1.z * r * s1.z); o1.w = f2bf(v1.w * r * s1.w);
    ushort4* hr = reinterpret_cast<ushort4*>(h + (size_t)row * 2048);
    hr[tid] = o0; hr[tid + 256] = o1;
}

// ---------------- K0: transpose-cast weights fp32 [K][N] -> bf16 [Npad][K] ----------------
__global__ __launch_bounds__(256) void k_wcast(const float* __restrict__ W,
                                               u16* __restrict__ Wt,
                                               int K, int N) {
    __shared__ u16 Ts[64][72];
    int n0 = blockIdx.x * 64, k0 = blockIdx.y * 64;
    int t = threadIdx.x;
    int jl = (t & 15) * 4;
#pragma unroll
    for (int s = 0; s < 4; ++s) {
        int kl = s * 16 + (t >> 4);
        if (n0 + jl + 4 <= N) {
            float4 v = *reinterpret_cast<const float4*>(W + (size_t)(k0 + kl) * N + n0 + jl);
            Ts[kl][jl] = f2bf(v.x); Ts[kl][jl + 1] = f2bf(v.y);
            Ts[kl][jl + 2] = f2bf(v.z); Ts[kl][jl + 3] = f2bf(v.w);
        } else {
#pragma unroll
            for (int e = 0; e < 4; ++e)
                Ts[kl][jl + e] = (n0 + jl + e < N) ? f2bf(W[(size_t)(k0 + kl) * N + n0 + jl + e]) : (u16)0;
        }
    }
    __syncthreads();
    int nl = t >> 2, kl0 = (t & 3) * 16;
    u16 tmp[16];
#pragma unroll
    for (int e = 0; e < 16; ++e) tmp[e] = Ts[kl0 + e][nl];
    u16* dst = Wt + (size_t)(n0 + nl) * K + k0 + kl0;
    *reinterpret_cast<uint4*>(dst) = *reinterpret_cast<uint4*>(tmp);
    *reinterpret_cast<uint4*>(dst + 8) = *reinterpret_cast<uint4*>(tmp + 8);
}

// ---------------- K2/K8: 128x128 MFMA GEMM, BK=64 (2 sub-tiles/barrier), swizzled 1D grid ----------------
template <bool BF16_OUT>
__global__ __launch_bounds__(256) void k_gemm128(const u16* __restrict__ A,
                                                 const u16* __restrict__ Bt,
                                                 u16* __restrict__ Cb,
                                                 float* __restrict__ Cf,
                                                 const float* __restrict__ resid,
                                                 int M, int Nout, int K) {
    __shared__ u16 As[8192];   // 2 halves x [128][32]
    __shared__ u16 Bs[8192];
    int mt = M >> 7;
    int bid = blockIdx.x;
    int grp = mt * 8;
    int g = bid / grp, l = bid % grp;
    int nb = g * 8 + (l & 7), mb = l >> 3;
    if (nb * 128 >= Nout) return;
    int m0 = mb * 128, n0 = nb * 128;

    int t = threadIdx.x, lane = t & 63, w = t >> 6;
    int row = t >> 2, kc = (t & 3) * 8;
    int wm = (w >> 1) * 64, wn = (w & 1) * 64;
    int r = lane & 15, q = lane >> 4;

    f32x4 acc[4][4];
#pragma unroll
    for (int a = 0; a < 4; ++a)
#pragma unroll
        for (int b = 0; b < 4; ++b) acc[a][b] = (f32x4){0.f, 0.f, 0.f, 0.f};

    const u16* ga0 = A + (size_t)(m0 + row) * K + kc;
    const u16* ga1 = A + (size_t)(m0 + 64 + row) * K + kc;
    const u16* gb0 = Bt + (size_t)(n0 + row) * K + kc;
    const u16* gb1 = Bt + (size_t)(n0 + 64 + row) * K + kc;

    for (int k0 = 0; k0 < K; k0 += 64) {
        load_lds16(ga0 + k0,      As + w * 512);
        load_lds16(ga1 + k0,      As + 2048 + w * 512);
        load_lds16(gb0 + k0,      Bs + w * 512);
        load_lds16(gb1 + k0,      Bs + 2048 + w * 512);
        load_lds16(ga0 + k0 + 32, As + 4096 + w * 512);
        load_lds16(ga1 + k0 + 32, As + 4096 + 2048 + w * 512);
        load_lds16(gb0 + k0 + 32, Bs + 4096 + w * 512);
        load_lds16(gb1 + k0 + 32, Bs + 4096 + 2048 + w * 512);
        __syncthreads();
#pragma unroll
        for (int h = 0; h < 2; ++h) {
            bf16x8 af[4], bf[4];
#pragma unroll
            for (int mi = 0; mi < 4; ++mi) af[mi] = ld8(&As[h * 4096 + (wm + mi * 16 + r) * 32 + q * 8]);
#pragma unroll
            for (int ni = 0; ni < 4; ++ni) bf[ni] = ld8(&Bs[h * 4096 + (wn + ni * 16 + r) * 32 + q * 8]);
#pragma unroll
            for (int mi = 0; mi < 4; ++mi)
#pragma unroll
                for (int ni = 0; ni < 4; ++ni)
                    acc[mi][ni] = __builtin_amdgcn_mfma_f32_16x16x32_bf16(af[mi], bf[ni], acc[mi][ni], 0, 0, 0);
        }
        __syncthreads();
    }
#pragma unroll
    for (int mi = 0; mi < 4; ++mi)
#pragma unroll
        for (int ni = 0; ni < 4; ++ni) {
            int gn = n0 + wn + ni * 16 + r;
            if (gn < Nout) {
#pragma unroll
                for (int rg = 0; rg < 4; ++rg) {
                    int gm = m0 + wm + mi * 16 + q * 4 + rg;
                    float vv = acc[mi][ni][rg];
                    if (BF16_OUT) {
                        Cb[(size_t)gm * Nout + gn] = f2bf(vv);
                    } else {
                        if (resid) vv += resid[(size_t)gm * Nout + gn];
                        Cf[(size_t)gm * Nout + gn] = vv;
                    }
                }
            }
        }
}

// ---------------- K4: dt=softplus, per-chunk inclusive cumsum of A*dt ----------------
__global__ __launch_bounds__(64) void k_dt(const u16* __restrict__ proj,
                                           const float* __restrict__ A_log,
                                           const float* __restrict__ dt_bias,
                                           float* __restrict__ dt,
                                           float* __restrict__ cumla) {
    int bid = blockIdx.x;
    int b = bid >> 10, hh = (bid >> 5) & 31, c = bid & 31;
    int j = threadIdx.x;
    int t = c * 64 + j;
    float z = bf2f(proj[(size_t)(b * 2048 + t) * 8480 + 8192 + hh]) + dt_bias[hh];
    float dtv = (z > 20.f) ? z : log1pf(expf(z));
    float v = -expf(A_log[hh]) * dtv;
#pragma unroll
    for (int off = 1; off < 64; off <<= 1) {
        float pv = __shfl_up(v, off, 64);
        if (j >= off) v += pv;
    }
    int base = ((b * 32 + hh) * 32 + c) * 64;
    dt[base + j] = dtv;
    cumla[base + j] = v;
}

// ---------------- K5: intra-chunk, conv+SiLU fused. ybuf = y_intra + D*X ----------------
__global__ __launch_bounds__(256) void k_intra(const u16* __restrict__ proj,
                                               const float* __restrict__ dt,
                                               const float* __restrict__ cumla,
                                               const float* __restrict__ cw,
                                               const float* __restrict__ cb,
                                               const float* __restrict__ Dv,
                                               u16* __restrict__ ybuf,
                                               u16* __restrict__ states) {
    __shared__ u16 Bs[64][136];
    __shared__ u16 Xt[128][72];
    __shared__ u16 Bt[128][72];
    __shared__ union {
        u16 Ms[64][72];                                   // used step1->step2
        struct { float cwl[4][128]; float cbl[128]; } cv; // used during staging only
    } sh;
    __shared__ float dts[64], clas[64];
    int bid = blockIdx.x;
    int b = bid >> 10, c = (bid >> 5) & 31, hh = bid & 31;
    int tid = threadIdx.x, lane = tid & 63, w = tid >> 6;
    int r = lane & 15, q = lane >> 4;
    int t0 = b * 2048 + c * 64;
    int sbase = ((b * 32 + hh) * 32 + c) * 64;

    if (tid < 64) { dts[tid] = dt[sbase + tid]; clas[tid] = cumla[sbase + tid]; }
    if (tid < 128) {
        sh.cv.cbl[tid] = cb[hh * 128 + tid];
#pragma unroll
        for (int k = 0; k < 4; ++k) sh.cv.cwl[k][tid] = cw[k * 4096 + hh * 128 + tid];
    }
    for (int e = tid; e < 1024; e += 256) {
        int i = e >> 4, n8 = (e & 15) * 8;
        *reinterpret_cast<uint4*>(&Bs[i][n8]) =
            *reinterpret_cast<const uint4*>(proj + (size_t)(t0 + i) * 8480 + 8224 + n8);
    }
    __syncthreads();

    // conv(4)+bias+SiLU -> Xt[p][j]; weighted B^T -> Bt[p][j]
    {
        int j = tid & 63;
        float wj = expf(clas[63] - clas[j]) * dts[j];
        for (int g = tid >> 6; g < 16; g += 4) {
            int p0 = g * 8;
            u16 tb[8];
            *reinterpret_cast<uint4*>(tb) = *reinterpret_cast<const uint4*>(&Bs[j][p0]);
            float xv[8];
#pragma unroll
            for (int e = 0; e < 8; ++e) xv[e] = sh.cv.cbl[p0 + e];
#pragma unroll
            for (int kk = 0; kk < 4; ++kk) {
                int tl = c * 64 + j - 3 + kk;
                if (tl >= 0) {
                    u16 srow[8];
                    *reinterpret_cast<uint4*>(srow) =
                        *reinterpret_cast<const uint4*>(proj + (size_t)(b * 2048 + tl) * 8480 + 4096 + hh * 128 + p0);
#pragma unroll
                    for (int e = 0; e < 8; ++e) xv[e] += sh.cv.cwl[kk][p0 + e] * bf2f(srow[e]);
                }
            }
#pragma unroll
            for (int e = 0; e < 8; ++e) {
                float s = xv[e] / (1.f + expf(-xv[e]));
                Xt[p0 + e][j] = f2bf(s);
                Bt[p0 + e][j] = f2bf(wj * bf2f(tb[e]));
            }
        }
    }
    __syncthreads();

    // step1: M = decay(C·B^T); C-fragments direct from global (L2-cached, 32x head reuse)
    {
        const u16* crow = proj + (size_t)(t0 + w * 16 + r) * 8480 + 8352;
        bf16x8 af[4];
#pragma unroll
        for (int k = 0; k < 4; ++k) af[k] = ld8(crow + k * 32 + q * 8);
#pragma unroll
        for (int tj = 0; tj < 4; ++tj) {
            f32x4 acc = (f32x4){0.f, 0.f, 0.f, 0.f};
#pragma unroll
            for (int k = 0; k < 4; ++k)
                acc = __builtin_amdgcn_mfma_f32_16x16x32_bf16(af[k], ld8(&Bs[tj * 16 + r][k * 32 + q * 8]), acc, 0, 0, 0);
            int j = tj * 16 + r;
            float dj = dts[j], cj = clas[j];
#pragma unroll
            for (int rg = 0; rg < 4; ++rg) {
                int i = w * 16 + q * 4 + rg;
                float m = (j <= i) ? acc[rg] * expf(clas[i] - cj) * dj : 0.f;
                sh.Ms[i][j] = f2bf(m);
            }
        }
    }
    __syncthreads();

    // step2: Y = M @ X + D*X
    {
        bf16x8 af[2];
#pragma unroll
        for (int k = 0; k < 2; ++k) af[k] = ld8(&sh.Ms[w * 16 + r][k * 32 + q * 8]);
#pragma unroll
        for (int tj = 0; tj < 8; ++tj) {
            f32x4 acc = (f32x4){0.f, 0.f, 0.f, 0.f};
#pragma unroll
            for (int k = 0; k < 2; ++k)
                acc = __builtin_amdgcn_mfma_f32_16x16x32_bf16(af[k], ld8(&Xt[tj * 16 + r][k * 32 + q * 8]), acc, 0, 0, 0);
            int p = tj * 16 + r;
            float dv = Dv[hh * 128 + p];
#pragma unroll
            for (int rg = 0; rg < 4; ++rg) {
                int i = w * 16 + q * 4 + rg;
                float v = acc[rg] + dv * bf2f(Xt[p][i]);
                ybuf[(size_t)(t0 + i) * 4096 + hh * 128 + p] = f2bf(v);
            }
        }
    }

    // step3: St[p][n] = sum_j Xt[p][j]*Bt[n][j]
    size_t sb = ((size_t)((b * 32 + hh) * 32 + c)) * 16384;
#pragma unroll
    for (int th = 0; th < 2; ++th) {
        int ti = w + th * 4;
        bf16x8 af[2];
#pragma unroll
        for (int k = 0; k < 2; ++k) af[k] = ld8(&Xt[ti * 16 + r][k * 32 + q * 8]);
#pragma unroll
        for (int tj = 0; tj < 8; ++tj) {
            f32x4 acc = (f32x4){0.f, 0.f, 0.f, 0.f};
#pragma unroll
            for (int k = 0; k < 2; ++k)
                acc = __builtin_amdgcn_mfma_f32_16x16x32_bf16(af[k], ld8(&Bt[tj * 16 + r][k * 32 + q * 8]), acc, 0, 0, 0);
            int n = tj * 16 + r;
#pragma unroll
            for (int rg = 0; rg < 4; ++rg) {
                int p = ti * 16 + q * 4 + rg;
                states[sb + p * 128 + n] = f2bf(acc[rg]);
            }
        }
    }
}

// ---------------- K6: inter-chunk sequential scan ----------------
__global__ __launch_bounds__(256) void k_scan(u16* __restrict__ states,
                                              const float* __restrict__ cumla) {
    int gid = blockIdx.x * 256 + threadIdx.x;
    int bh = gid >> 14;
    int np = gid & 16383;
    size_t base = (size_t)bh * 32 * 16384 + np;
    float s = 0.f;
    for (int c = 0; c < 32; ++c) {
        float cd = expf(cumla[(bh * 32 + c) * 64 + 63]);
        size_t idx = base + (size_t)c * 16384;
        float loc = bf2f(states[idx]);
        states[idx] = f2bf(s);
        s = cd * s + loc;
    }
}

// ---------------- K7: Y = ybuf + exp(cla)*C@S, SiLU gate ----------------
__global__ __launch_bounds__(256) void k_inter(const u16* __restrict__ proj,
                                               const u16* __restrict__ states,
                                               const float* __restrict__ cumla,
                                               const u16* __restrict__ ybuf,
                                               u16* __restrict__ ygated) {
    __shared__ u16 Ss[128][136];
    __shared__ float clav[64];
    int bid = blockIdx.x;
    int b = bid >> 10, c = (bid >> 5) & 31, hh = bid & 31;
    int tid = threadIdx.x, lane = tid & 63, w = tid >> 6;
    int r = lane & 15, q = lane >> 4;
    int t0 = b * 2048 + c * 64;
    int sbase = ((b * 32 + hh) * 32 + c) * 64;
    size_t sb = ((size_t)((b * 32 + hh) * 32 + c)) * 16384;

    if (tid < 64) clav[tid] = expf(cumla[sbase + tid]);
    for (int e = tid; e < 2048; e += 256) {
        int p = e >> 4, n8 = (e & 15) * 8;
        *reinterpret_cast<uint4*>(&Ss[p][n8]) =
            *reinterpret_cast<const uint4*>(states + sb + p * 128 + n8);
    }
    __syncthreads();

    const u16* crow = proj + (size_t)(t0 + w * 16 + r) * 8480 + 8352;
    bf16x8 af[4];
#pragma unroll
    for (int k = 0; k < 4; ++k) af[k] = ld8(crow + k * 32 + q * 8);
#pragma unroll
    for (int tj = 0; tj < 8; ++tj) {
        f32x4 acc = (f32x4){0.f, 0.f, 0.f, 0.f};
#pragma unroll
        for (int k = 0; k < 4; ++k)
            acc = __builtin_amdgcn_mfma_f32_16x16x32_bf16(af[k], ld8(&Ss[tj * 16 + r][k * 32 + q * 8]), acc, 0, 0, 0);
        int p = tj * 16 + r;
        int ch = hh * 128 + p;
#pragma unroll
        for (int rg = 0; rg < 4; ++rg) {
            int i = w * 16 + q * 4 + rg;
            size_t td = (size_t)(t0 + i) * 4096 + ch;
            float v = clav[i] * acc[rg] + bf2f(ybuf[td]);
            float g = bf2f(proj[(size_t)(t0 + i) * 8480 + ch]);
            ygated[td] = f2bf(v * (g / (1.f + expf(-g))));
        }
    }
}

extern "C" void kernel_launch(void* const* d_in, const int* in_sizes, int n_in,
                              void* d_out, int out_size, void* d_ws, size_t ws_size,
                              hipStream_t stream) {
    const float* x          = (const float*)d_in[0];
    const float* norm_scale = (const float*)d_in[1];
    const float* in_proj_w  = (const float*)d_in[2];
    const float* conv_w     = (const float*)d_in[3];
    const float* conv_b     = (const float*)d_in[4];
    const float* A_log      = (const float*)d_in[5];
    const float* dt_bias    = (const float*)d_in[6];
    const float* Dv         = (const float*)d_in[7];
    const float* out_w      = (const float*)d_in[8];
    float* out = (float*)d_out;

    char* ws = (char*)d_ws;
    // [0, 67.1M): states; h aliases [0, 16.8M) (dead before k_intra);
    // wbt aliases [16.8M, 51.9M) (dead after in_proj gemm).
    u16*   states = (u16*)(ws);
    u16*   h      = (u16*)(ws);
    u16*   wbt    = (u16*)(ws + 16777216);    // 8576x2048 bf16 = 35,127,296
    u16*   proj   = (u16*)(ws + 67108864);    // 69,468,160
    u16*   owt    = (u16*)(ws + 136577024);   // 2048x4096 bf16 = 16,777,216
    u16*   ybuf   = (u16*)(ws + 170131456);   // 33,554,432 (also ygated)
    float* dt     = (float*)(ws + 203685888); // 524,288
    float* cumla  = (float*)(ws + 204210176); // 524,288

    k_rmsnorm<<<4096, 256, 0, stream>>>(x, norm_scale, h);
    k_wcast<<<dim3(134, 32), 256, 0, stream>>>(in_proj_w, wbt, 2048, 8480);
    // in_proj: Ntiles=67 -> 9 groups of 8 -> 9*8*32 = 2304 blocks (ragged tail exits)
    k_gemm128<true><<<2304, 256, 0, stream>>>(h, wbt, proj, nullptr, nullptr, 4096, 8480, 2048);
    k_dt<<<2048, 64, 0, stream>>>(proj, A_log, dt_bias, dt, cumla);
    k_intra<<<2048, 256, 0, stream>>>(proj, dt, cumla, conv_w, conv_b, Dv, ybuf, states);
    k_scan<<<4096, 256, 0, stream>>>(states, cumla);
    k_inter<<<2048, 256, 0, stream>>>(proj, states, cumla, ybuf, ybuf);
    k_wcast<<<dim3(32, 64), 256, 0, stream>>>(out_w, owt, 4096, 2048);
    // out_proj: Ntiles=16 -> 2 groups -> 512 blocks
    k_gemm128<false><<<512, 256, 0, stream>>>(ybuf, owt, nullptr, out, x, 4096, 2048, 4096);
}

// Round 6
// 589.946 us; speedup vs baseline: 4.1640x; 1.0122x over previous
//
#include <hip/hip_runtime.h>

typedef unsigned short u16;
typedef unsigned short u16x8 __attribute__((ext_vector_type(8)));
typedef __bf16 bf16x8 __attribute__((ext_vector_type(8)));
typedef float f32x4 __attribute__((ext_vector_type(4)));

// B=2, T=2048, N_EMBD=2048, D_INNER=4096, N_HEADS=32, HEAD_DIM=128, D_STATE=128,
// PROJ=8480 (pad 8576), CHUNK=64, n_chunks=32. External tensors FP32; staging bf16.
// proj row: [0,4096) gate | [4096,8192) ssm_in | [8192,8224) dt | [8224,8352) B | [8352,8480) C

__device__ __forceinline__ float bf2f(u16 u) {
    union { unsigned int i; float f; } v; v.i = ((unsigned int)u) << 16; return v.f;
}
__device__ __forceinline__ u16 f2bf(float f) {
    unsigned int u = __float_as_uint(f);
    u += 0x7fffu + ((u >> 16) & 1u);   // RNE
    return (u16)(u >> 16);
}
__device__ __forceinline__ bf16x8 ld8(const u16* p) {
    return __builtin_bit_cast(bf16x8, *reinterpret_cast<const u16x8*>(p));
}
__device__ __forceinline__ void load_lds16(const u16* g, u16* l) {
    __builtin_amdgcn_global_load_lds(
        (const __attribute__((address_space(1))) unsigned int*)g,
        (__attribute__((address_space(3))) unsigned int*)l, 16, 0, 0);
}

// ---------------- K1: RMSNorm (fp32 in, bf16 out) ----------------
__global__ __launch_bounds__(256) void k_rmsnorm(const float* __restrict__ x,
                                                 const float* __restrict__ scale,
                                                 u16* __restrict__ h) {
    int row = blockIdx.x, tid = threadIdx.x;
    const float4* xr = reinterpret_cast<const float4*>(x + (size_t)row * 2048);
    float4 v0 = xr[tid], v1 = xr[tid + 256];
    float ss = v0.x*v0.x + v0.y*v0.y + v0.z*v0.z + v0.w*v0.w
             + v1.x*v1.x + v1.y*v1.y + v1.z*v1.z + v1.w*v1.w;
#pragma unroll
    for (int off = 32; off > 0; off >>= 1) ss += __shfl_down(ss, off, 64);
    __shared__ float red[4];
    if ((tid & 63) == 0) red[tid >> 6] = ss;
    __syncthreads();
    float r = rsqrtf((red[0] + red[1] + red[2] + red[3]) * (1.f / 2048.f) + 1e-6f);
    const float4* sc = reinterpret_cast<const float4*>(scale);
    float4 s0 = sc[tid], s1 = sc[tid + 256];
    ushort4 o0, o1;
    o0.x = f2bf(v0.x * r * s0.x); o0.y = f2bf(v0.y * r * s0.y);
    o0.z = f2bf(v0.z * r * s0.z); o0.w = f2bf(v0.w * r * s0.w);
    o1.x = f2bf(v1.x * r * s1.x); o1.y = f2bf(v1.y * r * s1.y);
    o1.z = f2bf(v1.z * r * s1.z); o1.w = f2bf(v1.w * r * s1.w);
    ushort4* hr = reinterpret_cast<ushort4*>(h + (size_t)row * 2048);
    hr[tid] = o0; hr[tid + 256] = o1;
}

// ---------------- K0: transpose-cast weights fp32 [K][N] -> bf16 [Npad][K] ----------------
__global__ __launch_bounds__(256) void k_wcast(const float* __restrict__ W,
                                               u16* __restrict__ Wt,
                                               int K, int N) {
    __shared__ u16 Ts[64][72];
    int n0 = blockIdx.x * 64, k0 = blockIdx.y * 64;
    int t = threadIdx.x;
    int jl = (t & 15) * 4;
#pragma unroll
    for (int s = 0; s < 4; ++s) {
        int kl = s * 16 + (t >> 4);
        if (n0 + jl + 4 <= N) {
            float4 v = *reinterpret_cast<const float4*>(W + (size_t)(k0 + kl) * N + n0 + jl);
            Ts[kl][jl] = f2bf(v.x); Ts[kl][jl + 1] = f2bf(v.y);
            Ts[kl][jl + 2] = f2bf(v.z); Ts[kl][jl + 3] = f2bf(v.w);
        } else {
#pragma unroll
            for (int e = 0; e < 4; ++e)
                Ts[kl][jl + e] = (n0 + jl + e < N) ? f2bf(W[(size_t)(k0 + kl) * N + n0 + jl + e]) : (u16)0;
        }
    }
    __syncthreads();
    int nl = t >> 2, kl0 = (t & 3) * 16;
    u16 tmp[16];
#pragma unroll
    for (int e = 0; e < 16; ++e) tmp[e] = Ts[kl0 + e][nl];
    u16* dst = Wt + (size_t)(n0 + nl) * K + k0 + kl0;
    *reinterpret_cast<uint4*>(dst) = *reinterpret_cast<uint4*>(tmp);
    *reinterpret_cast<uint4*>(dst + 8) = *reinterpret_cast<uint4*>(tmp + 8);
}

// ---------------- K2/K8: 128x128 MFMA GEMM, BK=64, swizzled 1D grid ----------------
template <bool BF16_OUT>
__global__ __launch_bounds__(256) void k_gemm128(const u16* __restrict__ A,
                                                 const u16* __restrict__ Bt,
                                                 u16* __restrict__ Cb,
                                                 float* __restrict__ Cf,
                                                 const float* __restrict__ resid,
                                                 int M, int Nout, int K) {
    __shared__ u16 As[8192];
    __shared__ u16 Bs[8192];
    int mt = M >> 7;
    int bid = blockIdx.x;
    int grp = mt * 8;
    int g = bid / grp, l = bid % grp;
    int nb = g * 8 + (l & 7), mb = l >> 3;
    if (nb * 128 >= Nout) return;
    int m0 = mb * 128, n0 = nb * 128;

    int t = threadIdx.x, lane = t & 63, w = t >> 6;
    int row = t >> 2, kc = (t & 3) * 8;
    int wm = (w >> 1) * 64, wn = (w & 1) * 64;
    int r = lane & 15, q = lane >> 4;

    f32x4 acc[4][4];
#pragma unroll
    for (int a = 0; a < 4; ++a)
#pragma unroll
        for (int b = 0; b < 4; ++b) acc[a][b] = (f32x4){0.f, 0.f, 0.f, 0.f};

    const u16* ga0 = A + (size_t)(m0 + row) * K + kc;
    const u16* ga1 = A + (size_t)(m0 + 64 + row) * K + kc;
    const u16* gb0 = Bt + (size_t)(n0 + row) * K + kc;
    const u16* gb1 = Bt + (size_t)(n0 + 64 + row) * K + kc;

    for (int k0 = 0; k0 < K; k0 += 64) {
        load_lds16(ga0 + k0,      As + w * 512);
        load_lds16(ga1 + k0,      As + 2048 + w * 512);
        load_lds16(gb0 + k0,      Bs + w * 512);
        load_lds16(gb1 + k0,      Bs + 2048 + w * 512);
        load_lds16(ga0 + k0 + 32, As + 4096 + w * 512);
        load_lds16(ga1 + k0 + 32, As + 4096 + 2048 + w * 512);
        load_lds16(gb0 + k0 + 32, Bs + 4096 + w * 512);
        load_lds16(gb1 + k0 + 32, Bs + 4096 + 2048 + w * 512);
        __syncthreads();
#pragma unroll
        for (int h = 0; h < 2; ++h) {
            bf16x8 af[4], bf[4];
#pragma unroll
            for (int mi = 0; mi < 4; ++mi) af[mi] = ld8(&As[h * 4096 + (wm + mi * 16 + r) * 32 + q * 8]);
#pragma unroll
            for (int ni = 0; ni < 4; ++ni) bf[ni] = ld8(&Bs[h * 4096 + (wn + ni * 16 + r) * 32 + q * 8]);
#pragma unroll
            for (int mi = 0; mi < 4; ++mi)
#pragma unroll
                for (int ni = 0; ni < 4; ++ni)
                    acc[mi][ni] = __builtin_amdgcn_mfma_f32_16x16x32_bf16(af[mi], bf[ni], acc[mi][ni], 0, 0, 0);
        }
        __syncthreads();
    }
#pragma unroll
    for (int mi = 0; mi < 4; ++mi)
#pragma unroll
        for (int ni = 0; ni < 4; ++ni) {
            int gn = n0 + wn + ni * 16 + r;
            if (gn < Nout) {
#pragma unroll
                for (int rg = 0; rg < 4; ++rg) {
                    int gm = m0 + wm + mi * 16 + q * 4 + rg;
                    float vv = acc[mi][ni][rg];
                    if (BF16_OUT) {
                        Cb[(size_t)gm * Nout + gn] = f2bf(vv);
                    } else {
                        if (resid) vv += resid[(size_t)gm * Nout + gn];
                        Cf[(size_t)gm * Nout + gn] = vv;
                    }
                }
            }
        }
}

// ---------------- K4: dt=softplus, per-chunk inclusive cumsum of A*dt ----------------
__global__ __launch_bounds__(64) void k_dt(const u16* __restrict__ proj,
                                           const float* __restrict__ A_log,
                                           const float* __restrict__ dt_bias,
                                           float* __restrict__ dt,
                                           float* __restrict__ cumla) {
    int bid = blockIdx.x;
    int b = bid >> 10, hh = (bid >> 5) & 31, c = bid & 31;
    int j = threadIdx.x;
    int t = c * 64 + j;
    float z = bf2f(proj[(size_t)(b * 2048 + t) * 8480 + 8192 + hh]) + dt_bias[hh];
    float dtv = (z > 20.f) ? z : log1pf(expf(z));
    float v = -expf(A_log[hh]) * dtv;
#pragma unroll
    for (int off = 1; off < 64; off <<= 1) {
        float pv = __shfl_up(v, off, 64);
        if (j >= off) v += pv;
    }
    int base = ((b * 32 + hh) * 32 + c) * 64;
    dt[base + j] = dtv;
    cumla[base + j] = v;
}

// ---------------- K5: intra-chunk, conv+SiLU fused; B/C fragments direct from global ----------------
__global__ __launch_bounds__(256) void k_intra(const u16* __restrict__ proj,
                                               const float* __restrict__ dt,
                                               const float* __restrict__ cumla,
                                               const float* __restrict__ cw,
                                               const float* __restrict__ cb,
                                               const float* __restrict__ Dv,
                                               u16* __restrict__ ybuf,
                                               u16* __restrict__ states) {
    __shared__ u16 Xt[128][72];
    __shared__ u16 Bt[128][72];
    __shared__ union {
        u16 Ms[64][72];                                   // step1 -> step2
        struct { float cwl[4][128]; float cbl[128]; } cv; // staging only
    } sh;
    __shared__ float dts[64], clas[64];
    int bid = blockIdx.x;
    int b = bid >> 10, c = (bid >> 5) & 31, hh = bid & 31;
    int tid = threadIdx.x, lane = tid & 63, w = tid >> 6;
    int r = lane & 15, q = lane >> 4;
    int t0 = b * 2048 + c * 64;
    int sbase = ((b * 32 + hh) * 32 + c) * 64;

    if (tid < 64) { dts[tid] = dt[sbase + tid]; clas[tid] = cumla[sbase + tid]; }
    if (tid < 128) {
        sh.cv.cbl[tid] = cb[hh * 128 + tid];
#pragma unroll
        for (int k = 0; k < 4; ++k) sh.cv.cwl[k][tid] = cw[k * 4096 + hh * 128 + tid];
    }
    __syncthreads();

    // conv(4)+bias+SiLU -> Xt[p][j]; weighted B^T -> Bt[p][j]  (B rows read from global/L2)
    {
        int j = tid & 63;
        float wj = expf(clas[63] - clas[j]) * dts[j];
        for (int g = tid >> 6; g < 16; g += 4) {
            int p0 = g * 8;
            u16 tb[8];
            *reinterpret_cast<uint4*>(tb) =
                *reinterpret_cast<const uint4*>(proj + (size_t)(t0 + j) * 8480 + 8224 + p0);
            float xv[8];
#pragma unroll
            for (int e = 0; e < 8; ++e) xv[e] = sh.cv.cbl[p0 + e];
#pragma unroll
            for (int kk = 0; kk < 4; ++kk) {
                int tl = c * 64 + j - 3 + kk;
                if (tl >= 0) {
                    u16 srow[8];
                    *reinterpret_cast<uint4*>(srow) =
                        *reinterpret_cast<const uint4*>(proj + (size_t)(b * 2048 + tl) * 8480 + 4096 + hh * 128 + p0);
#pragma unroll
                    for (int e = 0; e < 8; ++e) xv[e] += sh.cv.cwl[kk][p0 + e] * bf2f(srow[e]);
                }
            }
#pragma unroll
            for (int e = 0; e < 8; ++e) {
                float s = xv[e] / (1.f + expf(-xv[e]));
                Xt[p0 + e][j] = f2bf(s);
                Bt[p0 + e][j] = f2bf(wj * bf2f(tb[e]));
            }
        }
    }
    __syncthreads();

    // step1: M = decay(C·B^T); C and B fragments direct from global (32-head L2 reuse)
    {
        const u16* crow = proj + (size_t)(t0 + w * 16 + r) * 8480 + 8352;
        bf16x8 af[4];
#pragma unroll
        for (int k = 0; k < 4; ++k) af[k] = ld8(crow + k * 32 + q * 8);
#pragma unroll
        for (int tj = 0; tj < 4; ++tj) {
            const u16* brow = proj + (size_t)(t0 + tj * 16 + r) * 8480 + 8224;
            f32x4 acc = (f32x4){0.f, 0.f, 0.f, 0.f};
#pragma unroll
            for (int k = 0; k < 4; ++k)
                acc = __builtin_amdgcn_mfma_f32_16x16x32_bf16(af[k], ld8(brow + k * 32 + q * 8), acc, 0, 0, 0);
            int j = tj * 16 + r;
            float dj = dts[j], cj = clas[j];
#pragma unroll
            for (int rg = 0; rg < 4; ++rg) {
                int i = w * 16 + q * 4 + rg;
                float m = (j <= i) ? acc[rg] * expf(clas[i] - cj) * dj : 0.f;
                sh.Ms[i][j] = f2bf(m);
            }
        }
    }
    __syncthreads();

    // step2: Y = M @ X + D*X
    {
        bf16x8 af[2];
#pragma unroll
        for (int k = 0; k < 2; ++k) af[k] = ld8(&sh.Ms[w * 16 + r][k * 32 + q * 8]);
#pragma unroll
        for (int tj = 0; tj < 8; ++tj) {
            f32x4 acc = (f32x4){0.f, 0.f, 0.f, 0.f};
#pragma unroll
            for (int k = 0; k < 2; ++k)
                acc = __builtin_amdgcn_mfma_f32_16x16x32_bf16(af[k], ld8(&Xt[tj * 16 + r][k * 32 + q * 8]), acc, 0, 0, 0);
            int p = tj * 16 + r;
            float dv = Dv[hh * 128 + p];
#pragma unroll
            for (int rg = 0; rg < 4; ++rg) {
                int i = w * 16 + q * 4 + rg;
                float v = acc[rg] + dv * bf2f(Xt[p][i]);
                ybuf[(size_t)(t0 + i) * 4096 + hh * 128 + p] = f2bf(v);
            }
        }
    }

    // step3: St[p][n] = sum_j Xt[p][j]*Bt[n][j]
    size_t sb = ((size_t)((b * 32 + hh) * 32 + c)) * 16384;
#pragma unroll
    for (int th = 0; th < 2; ++th) {
        int ti = w + th * 4;
        bf16x8 af[2];
#pragma unroll
        for (int k = 0; k < 2; ++k) af[k] = ld8(&Xt[ti * 16 + r][k * 32 + q * 8]);
#pragma unroll
        for (int tj = 0; tj < 8; ++tj) {
            f32x4 acc = (f32x4){0.f, 0.f, 0.f, 0.f};
#pragma unroll
            for (int k = 0; k < 2; ++k)
                acc = __builtin_amdgcn_mfma_f32_16x16x32_bf16(af[k], ld8(&Bt[tj * 16 + r][k * 32 + q * 8]), acc, 0, 0, 0);
            int n = tj * 16 + r;
#pragma unroll
            for (int rg = 0; rg < 4; ++rg) {
                int p = ti * 16 + q * 4 + rg;
                states[sb + p * 128 + n] = f2bf(acc[rg]);
            }
        }
    }
}

// ---------------- K6: inter-chunk sequential scan, 4 elems/thread (8B vectors) ----------------
__global__ __launch_bounds__(256) void k_scan(u16* __restrict__ states,
                                              const float* __restrict__ cumla) {
    int gid = blockIdx.x * 256 + threadIdx.x;   // 262144 total
    int bh = gid >> 12;
    int q4 = (gid & 4095) * 4;
    size_t base = (size_t)bh * 32 * 16384 + q4;
    float s0 = 0.f, s1 = 0.f, s2 = 0.f, s3 = 0.f;
    for (int c = 0; c < 32; ++c) {
        float cd = expf(cumla[(bh * 32 + c) * 64 + 63]);
        size_t idx = base + (size_t)c * 16384;
        ushort4 v = *reinterpret_cast<ushort4*>(states + idx);
        float l0 = bf2f(v.x), l1 = bf2f(v.y), l2 = bf2f(v.z), l3 = bf2f(v.w);
        ushort4 o; o.x = f2bf(s0); o.y = f2bf(s1); o.z = f2bf(s2); o.w = f2bf(s3);
        *reinterpret_cast<ushort4*>(states + idx) = o;
        s0 = cd * s0 + l0; s1 = cd * s1 + l1; s2 = cd * s2 + l2; s3 = cd * s3 + l3;
    }
}

// ---------------- K7: Y = ybuf + exp(cla)*C@S, SiLU gate ----------------
__global__ __launch_bounds__(256) void k_inter(const u16* __restrict__ proj,
                                               const u16* __restrict__ states,
                                               const float* __restrict__ cumla,
                                               const u16* __restrict__ ybuf,
                                               u16* __restrict__ ygated) {
    __shared__ u16 Ss[128][136];
    __shared__ float clav[64];
    int bid = blockIdx.x;
    int b = bid >> 10, c = (bid >> 5) & 31, hh = bid & 31;
    int tid = threadIdx.x, lane = tid & 63, w = tid >> 6;
    int r = lane & 15, q = lane >> 4;
    int t0 = b * 2048 + c * 64;
    int sbase = ((b * 32 + hh) * 32 + c) * 64;
    size_t sb = ((size_t)((b * 32 + hh) * 32 + c)) * 16384;

    if (tid < 64) clav[tid] = expf(cumla[sbase + tid]);
    for (int e = tid; e < 2048; e += 256) {
        int p = e >> 4, n8 = (e & 15) * 8;
        *reinterpret_cast<uint4*>(&Ss[p][n8]) =
            *reinterpret_cast<const uint4*>(states + sb + p * 128 + n8);
    }
    __syncthreads();

    const u16* crow = proj + (size_t)(t0 + w * 16 + r) * 8480 + 8352;
    bf16x8 af[4];
#pragma unroll
    for (int k = 0; k < 4; ++k) af[k] = ld8(crow + k * 32 + q * 8);
#pragma unroll
    for (int tj = 0; tj < 8; ++tj) {
        f32x4 acc = (f32x4){0.f, 0.f, 0.f, 0.f};
#pragma unroll
        for (int k = 0; k < 4; ++k)
            acc = __builtin_amdgcn_mfma_f32_16x16x32_bf16(af[k], ld8(&Ss[tj * 16 + r][k * 32 + q * 8]), acc, 0, 0, 0);
        int p = tj * 16 + r;
        int ch = hh * 128 + p;
#pragma unroll
        for (int rg = 0; rg < 4; ++rg) {
            int i = w * 16 + q * 4 + rg;
            size_t td = (size_t)(t0 + i) * 4096 + ch;
            float v = clav[i] * acc[rg] + bf2f(ybuf[td]);
            float g = bf2f(proj[(size_t)(t0 + i) * 8480 + ch]);
            ygated[td] = f2bf(v * (g / (1.f + expf(-g))));
        }
    }
}

extern "C" void kernel_launch(void* const* d_in, const int* in_sizes, int n_in,
                              void* d_out, int out_size, void* d_ws, size_t ws_size,
                              hipStream_t stream) {
    const float* x          = (const float*)d_in[0];
    const float* norm_scale = (const float*)d_in[1];
    const float* in_proj_w  = (const float*)d_in[2];
    const float* conv_w     = (const float*)d_in[3];
    const float* conv_b     = (const float*)d_in[4];
    const float* A_log      = (const float*)d_in[5];
    const float* dt_bias    = (const float*)d_in[6];
    const float* Dv         = (const float*)d_in[7];
    const float* out_w      = (const float*)d_in[8];
    float* out = (float*)d_out;

    char* ws = (char*)d_ws;
    u16*   states = (u16*)(ws);               // 67,108,864 ; h aliases [0,16.8M), wbt [16.8M,51.9M)
    u16*   h      = (u16*)(ws);
    u16*   wbt    = (u16*)(ws + 16777216);    // 8576x2048 bf16
    u16*   proj   = (u16*)(ws + 67108864);    // 69,468,160
    u16*   owt    = (u16*)(ws + 136577024);   // 2048x4096 bf16
    u16*   ybuf   = (u16*)(ws + 170131456);   // 33,554,432 (also ygated)
    float* dt     = (float*)(ws + 203685888);
    float* cumla  = (float*)(ws + 204210176);

    k_rmsnorm<<<4096, 256, 0, stream>>>(x, norm_scale, h);
    k_wcast<<<dim3(134, 32), 256, 0, stream>>>(in_proj_w, wbt, 2048, 8480);
    k_gemm128<true><<<2304, 256, 0, stream>>>(h, wbt, proj, nullptr, nullptr, 4096, 8480, 2048);
    k_dt<<<2048, 64, 0, stream>>>(proj, A_log, dt_bias, dt, cumla);
    k_intra<<<2048, 256, 0, stream>>>(proj, dt, cumla, conv_w, conv_b, Dv, ybuf, states);
    k_scan<<<1024, 256, 0, stream>>>(states, cumla);
    k_inter<<<2048, 256, 0, stream>>>(proj, states, cumla, ybuf, ybuf);
    k_wcast<<<dim3(32, 64), 256, 0, stream>>>(out_w, owt, 4096, 2048);
    k_gemm128<false><<<512, 256, 0, stream>>>(ybuf, owt, nullptr, out, x, 4096, 2048, 4096);
}